// Round 8
// baseline (515.144 us; speedup 1.0000x reference)
//
#include <hip/hip_runtime.h>
#include <hip/hip_bf16.h>

#define VSZ   32000
#define EMBD  512
#define HIDD  1024
#define BB    64
#define TSEQ  512
#define G4    4096

typedef short bf16x8 __attribute__((ext_vector_type(8)));
typedef float f32x4  __attribute__((ext_vector_type(4)));

typedef __attribute__((address_space(3))) unsigned       lds_u32_t;
typedef __attribute__((address_space(1))) const unsigned glb_u32_t;
__device__ __forceinline__ void gload16(const void* g, void* l){
  __builtin_amdgcn_global_load_lds((glb_u32_t*)g, (lds_u32_t*)l, 16, 0, 0);
}

__device__ __forceinline__ float sigmoid_f(float x){ return 1.0f/(1.0f+__expf(-x)); }
__device__ __forceinline__ float fast_tanh(float x){
  float e = __expf(2.0f*x);
  return 1.0f - 2.0f*__builtin_amdgcn_rcpf(e + 1.0f);
}
__device__ __forceinline__ short f2bfs(float x){
  unsigned u = __float_as_uint(x);
  unsigned r = (u + 0x7FFFu + ((u>>16)&1u)) >> 16;
  return (short)r;
}
// single-instr packed f32x2 -> bf16x2 (RNE), gfx950
__device__ __forceinline__ unsigned cvtpk(float a, float b){
  unsigned r;
  asm("v_cvt_pk_bf16_f32 %0, %1, %2" : "=v"(r) : "v"(a), "v"(b));
  return r;
}
__device__ __forceinline__ bf16x8 cvt8(float4 a, float4 b){
  union { unsigned u[4]; bf16x8 v; } o;
  o.u[0]=cvtpk(a.x,a.y); o.u[1]=cvtpk(a.z,a.w);
  o.u[2]=cvtpk(b.x,b.y); o.u[3]=cvtpk(b.z,b.w);
  return o.v;
}
__device__ __forceinline__ float wave_sum(float x){
  #pragma unroll
  for (int off=32; off>0; off>>=1) x += __shfl_xor(x, off);
  return x;
}
__device__ __forceinline__ float wave_max(float x){
  #pragma unroll
  for (int off=32; off>0; off>>=1) x = fmaxf(x, __shfl_xor(x, off));
  return x;
}

// ---------------- pack Wk -> bf16 row-major, cols pre-XOR-swizzled within 64-chunks ----------------
// pk[a][c] = bf16(Wk[a][(c & ~63) | ((c & 63) ^ ((a&7)*8))])   (verified layout, round 4)
__global__ __launch_bounds__(256) void k_pack(const float* __restrict__ Wk,
                                              short* __restrict__ dst){
  int id = blockIdx.x*256 + threadIdx.x;   // 131072 = 1024a * 128g
  int a = id >> 7, g = id & 127;
  int gs = (g & ~7) | ((g & 7) ^ (a & 7));
  const float* src = Wk + (size_t)a*1024 + gs*8;
  float4 f0 = ((const float4*)src)[0], f1 = ((const float4*)src)[1];
  *(bf16x8*)(dst + (size_t)id*8) = cvt8(f0, f1);
}

// ---------------- prep: x_bf16[:,2560:3584] = bf16(h) ----------------
__global__ __launch_bounds__(256) void k_prep_h(const float* __restrict__ h,
                                                short* __restrict__ xb){
  int id = blockIdx.x*256 + threadIdx.x;     // 8192
  int b = id >> 7, d = (id & 127)*8;
  const float4* s = (const float4*)(h + (size_t)b*HIDD + d);
  *(bf16x8*)(xb + (size_t)b*3584 + 2560 + d) = cvt8(s[0], s[1]);
}

// ---------------- prep: x_bf16[:,0:2560] = bf16(emb|ctxe|ctxb), emb gathered ----------------
__global__ __launch_bounds__(256) void k_prep_x2(const float* __restrict__ tab,
                                                 const int* __restrict__ y,
                                                 const float* __restrict__ ctxe,
                                                 const float* __restrict__ ctxb,
                                                 short* __restrict__ xb){
  int id = blockIdx.x*256 + threadIdx.x;     // 20480
  if (id >= 64*320) return;
  int b = id / 320, off = (id % 320)*8;
  const float* src;
  if (off < 512)        src = tab  + (size_t)y[b]*EMBD + off;
  else if (off < 1536)  src = ctxe + (size_t)b*HIDD + (off-512);
  else                  src = ctxb + (size_t)b*HIDD + (off-1536);
  float4 f0 = ((const float4*)src)[0], f1 = ((const float4*)src)[1];
  *(bf16x8*)(xb + (size_t)b*3584 + off) = cvt8(f0, f1);
}

// ---------------- generic M=64 MFMA GEMM with K-split partials ----------------
__global__ __launch_bounds__(256) void k_mm64(
    const short* __restrict__ A0, int lda0, const float* __restrict__ B0, int ldb0, int K0, float* __restrict__ out0, int ldo0,
    const short* __restrict__ A1, int lda1, const float* __restrict__ B1, int ldb1, int K1, float* __restrict__ out1, int ldo1){
  const short* A; const float* B; float* out; int lda, ldb, K, ldo;
  if (blockIdx.z == 0){ A=A0; B=B0; out=out0; lda=lda0; ldb=ldb0; K=K0; ldo=ldo0; }
  else                { A=A1; B=B1; out=out1; lda=lda1; ldb=ldb1; K=K1; ldo=ldo1; }
  int tid = threadIdx.x, l = tid & 63, w = tid >> 6;
  int l15 = l & 15, l4 = l >> 4;
  int n0 = blockIdx.x*256 + w*64;
  int kper = K / gridDim.y;
  int dbeg = blockIdx.y * kper, dend = dbeg + kper;
  f32x4 acc[4][4];
  #pragma unroll
  for (int i=0;i<4;i++)
    #pragma unroll
    for (int j=0;j<4;j++)
      #pragma unroll
      for (int r=0;r<4;r++) acc[i][j][r]=0.f;
  for (int d0=dbeg; d0<dend; d0+=32){
    bf16x8 af[4];
    #pragma unroll
    for (int ms=0; ms<4; ms++)
      af[ms] = *(const bf16x8*)(A + (size_t)(ms*16 + l15)*lda + d0 + l4*8);
    bf16x8 bfr[4];
    #pragma unroll
    for (int ni=0; ni<4; ni++){
      const float* bp = B + (size_t)(n0 + ni*16 + l15)*ldb + d0 + l4*8;
      float4 f0 = ((const float4*)bp)[0], f1 = ((const float4*)bp)[1];
      bfr[ni] = cvt8(f0, f1);
    }
    #pragma unroll
    for (int ms=0; ms<4; ms++)
      #pragma unroll
      for (int ni=0; ni<4; ni++)
        acc[ms][ni] = __builtin_amdgcn_mfma_f32_16x16x32_bf16(af[ms], bfr[ni], acc[ms][ni], 0,0,0);
  }
  float* op = out + (size_t)blockIdx.y * 64 * ldo;
  #pragma unroll
  for (int ms=0; ms<4; ms++)
    #pragma unroll
    for (int ni=0; ni<4; ni++)
      #pragma unroll
      for (int r=0; r<4; r++){
        int m = ms*16 + l4*4 + r;
        op[(size_t)m*ldo + n0 + ni*16 + l15] = acc[ms][ni][r];
      }
}

// ---------------- K3: energy 128x128x1024 GEMM (m97 geometry) + fused tanh/v epilogue ----------------
// 4096 blocks x 256 thr (4 waves, 2x2, 4x4 acc of 16x16x32 = 64 AGPR -> 3 blocks/CU).
// A: keys f32 -> reg (1-deep prefetch) -> cvtpk -> swizzled LDS.
// B: pre-swizzled pk bf16 -> global_load_lds, DOUBLE-buffered, issued after the stage
//    barrier so loads fly across the whole MFMA phase.
__global__ __launch_bounds__(256,3) void k_energy(
    const float* __restrict__ enc, const float* __restrict__ bwd,
    const short* __restrict__ pke, const short* __restrict__ pkb,
    const float* __restrict__ qpe, const float* __restrict__ qpb,  // [2][64][1024] partials
    const float* __restrict__ ve, const float* __restrict__ vb,
    float* __restrict__ ep_out){                                   // [att][8][64][512]
  __shared__ short A_s[128*64];       // 16 KB, XOR-swizzled rows
  __shared__ short B_s[2][128*64];    // 2 x 16 KB (pre-swizzled via global layout)
  __shared__ float ebuf[2][128];

  int wg = blockIdx.x;
  int xcd = wg & 7, idx = wg >> 3;
  int tglob = xcd*64 + (idx >> 3);    // 0..511
  int A0 = idx & 7;                   // a-tile (innermost -> A-tile L2 reuse)
  int att = tglob >> 8;
  int tt  = tglob & 255;
  int b = tt >> 2, t0 = (tt & 3)*128;

  const float* keys = att ? bwd : enc;
  const short* pk   = att ? pkb : pke;
  const float* qp   = att ? qpb : qpe;
  const float* v    = att ? vb  : ve;

  int tid = threadIdx.x, l = tid & 63, w = tid >> 6;
  int l15 = l & 15, l4 = l >> 4;
  int wr = w >> 1, wc = w & 1;

  // A staging map: row sr = tid>>1 (0..127), half hf = tid&1 (32 floats each)
  int sr = tid >> 1, hf = tid & 1;
  const float4* asrc4 = (const float4*)(keys + ((size_t)b*TSEQ + t0 + sr)*1024 + hf*32);
  char* awr = (char*)A_s + sr*128;
  int sw = (sr & 7) << 4;
  int aw0 = (hf*64 +  0) ^ sw;
  int aw1 = (hf*64 + 16) ^ sw;
  int aw2 = (hf*64 + 32) ^ sw;
  int aw3 = (hf*64 + 48) ^ sw;

  // B gload source (pre-swizzled pk), linear LDS dest (wave-uniform base + lane*16)
  const char* bsrc = (const char*)pk + ((size_t)(A0*128 + w*32 + (l>>3)))*2048 + (l&7)*16;

  f32x4 acc[4][4];
  #pragma unroll
  for (int i=0;i<4;i++)
    #pragma unroll
    for (int j=0;j<4;j++)
      #pragma unroll
      for (int r=0;r<4;r++) acc[i][j][r]=0.f;

  float4 st[8];
  #pragma unroll
  for (int i=0;i<8;i++) st[i] = asrc4[i];          // A chunk 0
  #pragma unroll
  for (int k=0;k<4;k++)                             // B chunk 0 -> buf 0
    gload16(bsrc + (size_t)k*16384, (char*)B_s[0] + w*4096 + k*1024);

#define STAGE_A() \
    *(bf16x8*)(awr + aw0) = cvt8(st[0], st[1]); \
    *(bf16x8*)(awr + aw1) = cvt8(st[2], st[3]); \
    *(bf16x8*)(awr + aw2) = cvt8(st[4], st[5]); \
    *(bf16x8*)(awr + aw3) = cvt8(st[6], st[7]);

#define MFMA_PHASE(BUFBASE) \
    _Pragma("unroll") \
    for (int ks=0; ks<2; ks++){ \
      bf16x8 af[4], bf[4]; \
      _Pragma("unroll") \
      for (int ms=0; ms<4; ms++){ \
        int row = wr*64 + ms*16 + l15; \
        af[ms] = *(const bf16x8*)((char*)A_s + row*128 + ((ks*64 + l4*16) ^ ((row&7)<<4))); \
      } \
      _Pragma("unroll") \
      for (int ni=0; ni<4; ni++){ \
        int row = wc*64 + ni*16 + l15; \
        bf[ni] = *(const bf16x8*)((BUFBASE) + row*128 + ((ks*64 + l4*16) ^ ((row&7)<<4))); \
      } \
      _Pragma("unroll") \
      for (int ms=0; ms<4; ms++) \
        _Pragma("unroll") \
        for (int ni=0; ni<4; ni++) \
          acc[ms][ni] = __builtin_amdgcn_mfma_f32_16x16x32_bf16(af[ms], bf[ni], acc[ms][ni], 0,0,0); \
    }

  for (int cc=0; cc<16; cc+=2){
    // ---- even chunk cc (B buf 0) ----
    if (cc) __syncthreads();              // all waves done reading prev LDS
    STAGE_A();
    __syncthreads();                      // drains gload(B,cc) + A ds_writes
    if (cc+1 < 16){                       // A prefetch (chunk cc+1) overlaps MFMA
      #pragma unroll
      for (int i=0;i<8;i++) st[i] = asrc4[(cc+1)*16 + i];
      #pragma unroll
      for (int k=0;k<4;k++)               // B(cc+1) -> buf1, flies across MFMA phase
        gload16(bsrc + (size_t)(cc+1)*128 + (size_t)k*16384, (char*)B_s[1] + w*4096 + k*1024);
    }
    MFMA_PHASE((char*)B_s[0]);
    // ---- odd chunk cc+1 (B buf 1) ----
    __syncthreads();
    STAGE_A();
    __syncthreads();
    if (cc+2 < 16){
      #pragma unroll
      for (int i=0;i<8;i++) st[i] = asrc4[(cc+2)*16 + i];
      #pragma unroll
      for (int k=0;k<4;k++)
        gload16(bsrc + (size_t)(cc+2)*128 + (size_t)k*16384, (char*)B_s[0] + w*4096 + k*1024);
    }
    MFMA_PHASE((char*)B_s[1]);
  }
#undef STAGE_A
#undef MFMA_PHASE

  // fused epilogue: e_part[t] = sum_a v[a]*tanh(q[a] + P[t][a]) over this block's 128 a's
  float qv[4], vv[4];
  #pragma unroll
  for (int ni=0; ni<4; ni++){
    int a = A0*128 + wc*64 + ni*16 + l15;
    qv[ni] = qp[(size_t)b*HIDD + a] + qp[65536 + (size_t)b*HIDD + a];
    vv[ni] = v[a];
  }
  float es[16];
  #pragma unroll
  for (int ms=0; ms<4; ms++)
    #pragma unroll
    for (int r=0; r<4; r++){
      float s = 0.f;
      #pragma unroll
      for (int ni=0; ni<4; ni++)
        s += vv[ni]*fast_tanh(qv[ni] + acc[ms][ni][r]);
      es[ms*4+r] = s;
    }
  #pragma unroll
  for (int i=0;i<16;i++){
    float x = es[i];
    x += __shfl_xor(x,1); x += __shfl_xor(x,2);
    x += __shfl_xor(x,4); x += __shfl_xor(x,8);
    es[i] = x;
  }
  if (l15 == 0){
    #pragma unroll
    for (int ms=0; ms<4; ms++)
      #pragma unroll
      for (int r=0; r<4; r++)
        ebuf[wc][wr*64 + ms*16 + l4*4 + r] = es[ms*4+r];
  }
  __syncthreads();
  if (tid < 128)
    ep_out[(((size_t)att*8 + A0)*BB + b)*TSEQ + t0 + tid] = ebuf[0][tid] + ebuf[1][tid];
}

// ---------------- K4: softmax over T (sums 8 a-tile partials, applies mask) ----------------
__global__ __launch_bounds__(256) void k_softmax_t(const float* __restrict__ ep,
                                                   const int* __restrict__ mask,
                                                   float* __restrict__ att_e,
                                                   float* __restrict__ att_b){
  int b = blockIdx.x, att = blockIdx.y;
  float* e = (att ? att_b : att_e) + (size_t)b*TSEQ;
  __shared__ float red[8];
  int tid = threadIdx.x, lane = tid & 63, w = tid >> 6;
  float v0 = 0.f, v1 = 0.f;
  #pragma unroll
  for (int i=0;i<8;i++){
    const float* p = ep + (((size_t)att*8 + i)*BB + b)*TSEQ;
    v0 += p[tid]; v1 += p[tid+256];
  }
  if (att==0){
    if (mask[(size_t)b*TSEQ + tid]==0)      v0 = -3.4e38f;
    if (mask[(size_t)b*TSEQ + tid+256]==0)  v1 = -3.4e38f;
  }
  float m = wave_max(fmaxf(v0, v1));
  if (lane==0) red[w] = m;
  __syncthreads();
  m = fmaxf(fmaxf(red[0],red[1]), fmaxf(red[2],red[3]));
  float x0 = __expf(v0-m), x1 = __expf(v1-m);
  float s = wave_sum(x0+x1);
  if (lane==0) red[4+w] = s;
  __syncthreads();
  s = red[4]+red[5]+red[6]+red[7];
  float inv = 1.0f/s;
  e[tid] = x0*inv; e[tid+256] = x1*inv;
}

// ---------------- K5: context = attn @ keys (float4-vectorized) ----------------
__global__ __launch_bounds__(256) void k_ctx(const float* __restrict__ enc,
                                             const float* __restrict__ bwdst,
                                             const float* __restrict__ att_e,
                                             const float* __restrict__ att_b,
                                             float* __restrict__ ctxp){
  int b = blockIdx.x, sel = blockIdx.y, s = blockIdx.z;
  const float4* keys4 = (const float4*)((sel ? bwdst : enc) + ((size_t)b*TSEQ + s*64)*1024);
  const float* att  = (sel ? att_b : att_e) + (size_t)b*TSEQ + s*64;
  int tid = threadIdx.x;
  float ax=0.f, ay=0.f, az=0.f, aw=0.f;
  for (int t=0;t<64;t++){
    float a = att[t];
    float4 kv = keys4[(size_t)t*256 + tid];
    ax += a*kv.x; ay += a*kv.y; az += a*kv.z; aw += a*kv.w;
  }
  float4 o; o.x=ax; o.y=ay; o.z=az; o.w=aw;
  ((float4*)(ctxp + (((size_t)sel*BB + b)*8 + s)*1024))[tid] = o;
}

__global__ __launch_bounds__(256) void k_ctxred(const float* __restrict__ ctxp,
                                                float* __restrict__ ctx_e,
                                                float* __restrict__ ctx_b){
  int id = blockIdx.x*256 + threadIdx.x;
  int sel = id >> 16; int rem = id & 65535; int b = rem >> 10; int d = rem & 1023;
  const float* p = ctxp + (((size_t)sel*BB + b)*8)*1024 + d;
  float s = 0.f;
  #pragma unroll
  for (int i=0;i<8;i++) s += p[i*1024];
  (sel ? ctx_b : ctx_e)[(size_t)b*HIDD + d] = s;
}

// ---------------- K7: LSTM cell (8-slot partial reduce) + bf16 h_new ----------------
__global__ __launch_bounds__(256) void k_lstm(const float* __restrict__ gp,
                                              const float* __restrict__ b_ih,
                                              const float* __restrict__ b_hh,
                                              const float* __restrict__ c_old,
                                              float* __restrict__ out,
                                              short* __restrict__ hb){
  int id = blockIdx.x*256 + threadIdx.x;    // 65536
  int b = id >> 10, j = id & 1023;
  size_t base = (size_t)b*G4;
  float gs[4];
  #pragma unroll
  for (int g=0; g<4; g++){
    int col = g*1024 + j;
    float s = b_ih[col] + b_hh[col];
    #pragma unroll
    for (int k=0;k<8;k++) s += gp[(size_t)k*(64*G4) + base + col];
    gs[g] = s;
  }
  float ig = sigmoid_f(gs[0]);
  float fg = sigmoid_f(gs[1]);
  float gg = tanhf(gs[2]);
  float og = sigmoid_f(gs[3]);
  float cn = fg*c_old[id] + ig*gg;
  float hn = og*tanhf(cn);
  out[(size_t)BB*VSZ + id] = hn;
  out[(size_t)BB*VSZ + (size_t)BB*HIDD + id] = cn;
  hb[id] = f2bfs(hn);
}

// ---------------- K8: vocab logits via MFMA, N=128/block (250 blocks) ----------------
__global__ __launch_bounds__(256) void k_vocab2(const short* __restrict__ hb,
                                                const float* __restrict__ Wp,
                                                const float* __restrict__ bp,
                                                float* __restrict__ out){
  int tid = threadIdx.x, l = tid & 63, w = tid >> 6;
  int l15 = l & 15, l4 = l >> 4;
  int mh = w >> 1;
  int n0 = blockIdx.x*128 + (w&1)*64;
  f32x4 acc[2][4];
  #pragma unroll
  for (int i=0;i<2;i++)
    #pragma unroll
    for (int j=0;j<4;j++)
      #pragma unroll
      for (int r=0;r<4;r++) acc[i][j][r]=0.f;
  for (int d0=0; d0<1024; d0+=32){
    bf16x8 af[2];
    #pragma unroll
    for (int ms=0; ms<2; ms++)
      af[ms] = *(const bf16x8*)(hb + (size_t)(mh*32 + ms*16 + l15)*1024 + d0 + l4*8);
    bf16x8 bfr[4];
    #pragma unroll
    for (int ni=0; ni<4; ni++){
      const float* bpp = Wp + (size_t)(n0 + ni*16 + l15)*1024 + d0 + l4*8;
      float4 f0 = ((const float4*)bpp)[0], f1 = ((const float4*)bpp)[1];
      bfr[ni] = cvt8(f0, f1);
    }
    #pragma unroll
    for (int ms=0; ms<2; ms++)
      #pragma unroll
      for (int ni=0; ni<4; ni++)
        acc[ms][ni] = __builtin_amdgcn_mfma_f32_16x16x32_bf16(af[ms], bfr[ni], acc[ms][ni], 0,0,0);
  }
  #pragma unroll
  for (int ms=0; ms<2; ms++)
    #pragma unroll
    for (int ni=0; ni<4; ni++)
      #pragma unroll
      for (int r=0; r<4; r++){
        int m = mh*32 + ms*16 + l4*4 + r;
        int n = n0 + ni*16 + l15;
        out[(size_t)m*VSZ + n] = acc[ms][ni][r] + bp[n];
      }
}

// ---------------- K9: p_gen + softmax(V), 1024 threads ----------------
__global__ __launch_bounds__(1024) void k_final(const float* __restrict__ ctxe,
                                                const float* __restrict__ tab,
                                                const int* __restrict__ y,
                                                const float* __restrict__ wc,
                                                const float* __restrict__ wsv,
                                                const float* __restrict__ wy,
                                                const float* __restrict__ pgb,
                                                float* __restrict__ out,
                                                float* __restrict__ pgen_ws){
  __shared__ float red[32];
  int b = blockIdx.x, tid = threadIdx.x, lane = tid & 63, w = tid >> 6;
  const float* hn = out + (size_t)BB*VSZ + (size_t)b*HIDD;
  float acc = ctxe[(size_t)b*HIDD + tid]*wc[tid] + hn[tid]*wsv[tid];
  if (tid < 512) acc += tab[(size_t)y[b]*EMBD + tid]*wy[tid];
  acc = wave_sum(acc);
  if (lane==0) red[w] = acc;
  __syncthreads();
  float s0 = pgb[0];
  #pragma unroll
  for (int i=0;i<16;i++) s0 += red[i];
  float pg = sigmoid_f(s0);
  if (tid==0) pgen_ws[b] = pg;
  __syncthreads();

  float* row = out + (size_t)b*VSZ;
  float m = -3.4e38f;
  for (int i=tid;i<VSZ;i+=1024) m = fmaxf(m, row[i]);
  m = wave_max(m);
  if (lane==0) red[w] = m;
  __syncthreads();
  #pragma unroll
  for (int i=0;i<16;i++) m = fmaxf(m, red[i]);
  float s = 0.f;
  for (int i=tid;i<VSZ;i+=1024) s += __expf(row[i]-m);
  s = wave_sum(s);
  if (lane==0) red[16+w] = s;
  __syncthreads();
  float tot = 0.f;
  #pragma unroll
  for (int i=0;i<16;i++) tot += red[16+i];
  float scale = pg / tot;
  for (int i=tid;i<VSZ;i+=1024) row[i] = __expf(row[i]-m)*scale;
}

// ---------------- K10: pointer scatter ----------------
__global__ __launch_bounds__(256) void k_scatter(const int* __restrict__ src_ids,
                                                 const float* __restrict__ att_e,
                                                 const float* __restrict__ pgen_ws,
                                                 float* __restrict__ out){
  int id = blockIdx.x*256 + threadIdx.x;
  int b = id >> 9;
  float pg = pgen_ws[b];
  int sid = src_ids[id];
  float contrib = (1.0f - pg) * att_e[id] * (sid < VSZ ? 1.0f : 0.0f);
  int safe = sid < VSZ-1 ? sid : VSZ-1;
  atomicAdd(&out[(size_t)b*VSZ + safe], contrib);
}

extern "C" void kernel_launch(void* const* d_in, const int* in_sizes, int n_in,
                              void* d_out, int out_size, void* d_ws, size_t ws_size,
                              hipStream_t stream){
  const int*   y     = (const int*)d_in[0];
  const float* h     = (const float*)d_in[1];
  const float* c     = (const float*)d_in[2];
  const float* enc   = (const float*)d_in[3];
  const float* bwd   = (const float*)d_in[4];
  const int*   sids  = (const int*)d_in[5];
  const int*   smask = (const int*)d_in[6];
  const float* tab   = (const float*)d_in[7];
  const float* W_ih  = (const float*)d_in[8];
  const float* W_hh  = (const float*)d_in[9];
  const float* b_ih  = (const float*)d_in[10];
  const float* b_hh  = (const float*)d_in[11];
  const float* Wq_e  = (const float*)d_in[12];
  const float* Wk_e  = (const float*)d_in[13];
  const float* v_e   = (const float*)d_in[14];
  const float* Wq_b  = (const float*)d_in[15];
  const float* Wk_b  = (const float*)d_in[16];
  const float* v_b   = (const float*)d_in[17];
  const float* Wp    = (const float*)d_in[18];
  const float* bp    = (const float*)d_in[19];
  const float* wc    = (const float*)d_in[20];
  const float* wsv   = (const float*)d_in[21];
  const float* wy    = (const float*)d_in[22];
  const float* pgb   = (const float*)d_in[23];
  float* out = (float*)d_out;

  float* W = (float*)d_ws;
  float* ws_qpe  = W; W += 2*BB*HIDD;        // qproj partials (2 K-split slots)
  float* ws_qpb  = W; W += 2*BB*HIDD;
  float* ws_ep   = W; W += 2*8*BB*TSEQ;      // energy partials [att][8][b][t]
  float* ws_atte = W; W += BB*TSEQ;
  float* ws_attb = W; W += BB*TSEQ;
  float* ws_ctxe = W; W += BB*HIDD;
  float* ws_ctxb = W; W += BB*HIDD;
  float* ws_ctxp = W; W += 2*BB*8*1024;      // 1048576
  float* ws_pgen = W; W += 64;
  float* ws_gp   = W; W += 8*BB*G4;          // 2097152 (8 K-split slots)
  short* xb      = (short*)W; W += (BB*3584)/2;
  short* hb      = (short*)W; W += (BB*HIDD)/2;
  short* pk_e    = (short*)W; W += (HIDD*HIDD)/2;   // packed+swizzled Wk_e bf16
  short* pk_b    = (short*)W; W += (HIDD*HIDD)/2;

  k_pack<<<512, 256, 0, stream>>>(Wk_e, pk_e);
  k_pack<<<512, 256, 0, stream>>>(Wk_b, pk_b);
  k_prep_h<<<32, 256, 0, stream>>>(h, xb);
  k_mm64<<<dim3(4,2,2), 256, 0, stream>>>(
      xb+2560, 3584, Wq_e, 1024, 1024, ws_qpe, 1024,
      xb+2560, 3584, Wq_b, 1024, 1024, ws_qpb, 1024);
  k_energy<<<4096, 256, 0, stream>>>(enc, bwd, pk_e, pk_b,
      ws_qpe, ws_qpb, v_e, v_b, ws_ep);
  k_softmax_t<<<dim3(BB,2), 256, 0, stream>>>(ws_ep, smask, ws_atte, ws_attb);
  k_ctx<<<dim3(BB,2,8), 256, 0, stream>>>(enc, bwd, ws_atte, ws_attb, ws_ctxp);
  k_ctxred<<<512, 256, 0, stream>>>(ws_ctxp, ws_ctxe, ws_ctxb);
  k_prep_x2<<<80, 256, 0, stream>>>(tab, y, ws_ctxe, ws_ctxb, xb);
  k_mm64<<<dim3(16,4,2), 256, 0, stream>>>(
      xb,      3584, W_ih, 2560, 2560, ws_gp,             G4,
      xb+2560, 3584, W_hh, 1024, 1024, ws_gp + 4*BB*G4,   G4);
  k_lstm<<<256, 256, 0, stream>>>(ws_gp, b_ih, b_hh, c, out, hb);
  k_vocab2<<<250, 256, 0, stream>>>(hb, Wp, bp, out);
  k_final<<<BB, 1024, 0, stream>>>(ws_ctxe, tab, y, wc, wsv, wy, pgb, out, ws_pgen);
  k_scatter<<<128, 256, 0, stream>>>(sids, ws_atte, ws_pgen, out);
}

// Round 9
// 416.408 us; speedup vs baseline: 1.2371x; 1.2371x over previous
//
#include <hip/hip_runtime.h>
#include <hip/hip_bf16.h>

#define VSZ   32000
#define EMBD  512
#define HIDD  1024
#define BB    64
#define TSEQ  512
#define G4    4096

typedef short bf16x8 __attribute__((ext_vector_type(8)));
typedef float f32x4  __attribute__((ext_vector_type(4)));

__device__ __forceinline__ float sigmoid_f(float x){ return 1.0f/(1.0f+__expf(-x)); }
__device__ __forceinline__ float fast_tanh(float x){
  float e = __expf(2.0f*x);
  return 1.0f - 2.0f*__builtin_amdgcn_rcpf(e + 1.0f);
}
__device__ __forceinline__ short f2bfs(float x){
  unsigned u = __float_as_uint(x);
  unsigned r = (u + 0x7FFFu + ((u>>16)&1u)) >> 16;
  return (short)r;
}
// single-instr packed f32x2 -> bf16x2 (RNE), gfx950
__device__ __forceinline__ unsigned cvtpk(float a, float b){
  unsigned r;
  asm("v_cvt_pk_bf16_f32 %0, %1, %2" : "=v"(r) : "v"(a), "v"(b));
  return r;
}
__device__ __forceinline__ bf16x8 cvt8(float4 a, float4 b){
  union { unsigned u[4]; bf16x8 v; } o;
  o.u[0]=cvtpk(a.x,a.y); o.u[1]=cvtpk(a.z,a.w);
  o.u[2]=cvtpk(b.x,b.y); o.u[3]=cvtpk(b.z,b.w);
  return o.v;
}
__device__ __forceinline__ float wave_sum(float x){
  #pragma unroll
  for (int off=32; off>0; off>>=1) x += __shfl_xor(x, off);
  return x;
}
__device__ __forceinline__ float wave_max(float x){
  #pragma unroll
  for (int off=32; off>0; off>>=1) x = fmaxf(x, __shfl_xor(x, off));
  return x;
}

// ---------------- pack Wk into 16x16x32 MFMA B-fragment order, f32 -> bf16 ----------------
// dst[((nt*32 + s)*64 + l)*8 + j] = Wk[nt*16 + (l&15)][s*32 + (l>>4)*8 + j]
__global__ __launch_bounds__(256) void k_pack(const float* __restrict__ Wk,
                                              short* __restrict__ dst){
  int id = blockIdx.x*256 + threadIdx.x;   // 131072 = 64nt * 32s * 64l
  int l = id & 63, s = (id>>6) & 31, nt = id >> 11;
  const float* src = Wk + (size_t)(nt*16 + (l&15))*1024 + s*32 + (l>>4)*8;
  float4 f0 = ((const float4*)src)[0], f1 = ((const float4*)src)[1];
  *(bf16x8*)(dst + (size_t)id*8) = cvt8(f0, f1);
}

// ---------------- prep: x_bf16[:,2560:3584] = bf16(h) ----------------
__global__ __launch_bounds__(256) void k_prep_h(const float* __restrict__ h,
                                                short* __restrict__ xb){
  int id = blockIdx.x*256 + threadIdx.x;     // 8192
  int b = id >> 7, d = (id & 127)*8;
  const float4* s = (const float4*)(h + (size_t)b*HIDD + d);
  *(bf16x8*)(xb + (size_t)b*3584 + 2560 + d) = cvt8(s[0], s[1]);
}

// ---------------- prep: x_bf16[:,0:2560] = bf16(emb|ctxe|ctxb), emb gathered ----------------
__global__ __launch_bounds__(256) void k_prep_x2(const float* __restrict__ tab,
                                                 const int* __restrict__ y,
                                                 const float* __restrict__ ctxe,
                                                 const float* __restrict__ ctxb,
                                                 short* __restrict__ xb){
  int id = blockIdx.x*256 + threadIdx.x;     // 20480
  if (id >= 64*320) return;
  int b = id / 320, off = (id % 320)*8;
  const float* src;
  if (off < 512)        src = tab  + (size_t)y[b]*EMBD + off;
  else if (off < 1536)  src = ctxe + (size_t)b*HIDD + (off-512);
  else                  src = ctxb + (size_t)b*HIDD + (off-1536);
  float4 f0 = ((const float4*)src)[0], f1 = ((const float4*)src)[1];
  *(bf16x8*)(xb + (size_t)b*3584 + off) = cvt8(f0, f1);
}

// ---------------- generic M=64 MFMA GEMM with K-split partials ----------------
__global__ __launch_bounds__(256) void k_mm64(
    const short* __restrict__ A0, int lda0, const float* __restrict__ B0, int ldb0, int K0, float* __restrict__ out0, int ldo0,
    const short* __restrict__ A1, int lda1, const float* __restrict__ B1, int ldb1, int K1, float* __restrict__ out1, int ldo1){
  const short* A; const float* B; float* out; int lda, ldb, K, ldo;
  if (blockIdx.z == 0){ A=A0; B=B0; out=out0; lda=lda0; ldb=ldb0; K=K0; ldo=ldo0; }
  else                { A=A1; B=B1; out=out1; lda=lda1; ldb=ldb1; K=K1; ldo=ldo1; }
  int tid = threadIdx.x, l = tid & 63, w = tid >> 6;
  int l15 = l & 15, l4 = l >> 4;
  int n0 = blockIdx.x*256 + w*64;
  int kper = K / gridDim.y;
  int dbeg = blockIdx.y * kper, dend = dbeg + kper;
  f32x4 acc[4][4];
  #pragma unroll
  for (int i=0;i<4;i++)
    #pragma unroll
    for (int j=0;j<4;j++)
      #pragma unroll
      for (int r=0;r<4;r++) acc[i][j][r]=0.f;
  for (int d0=dbeg; d0<dend; d0+=32){
    bf16x8 af[4];
    #pragma unroll
    for (int ms=0; ms<4; ms++)
      af[ms] = *(const bf16x8*)(A + (size_t)(ms*16 + l15)*lda + d0 + l4*8);
    bf16x8 bfr[4];
    #pragma unroll
    for (int ni=0; ni<4; ni++){
      const float* bp = B + (size_t)(n0 + ni*16 + l15)*ldb + d0 + l4*8;
      float4 f0 = ((const float4*)bp)[0], f1 = ((const float4*)bp)[1];
      bfr[ni] = cvt8(f0, f1);
    }
    #pragma unroll
    for (int ms=0; ms<4; ms++)
      #pragma unroll
      for (int ni=0; ni<4; ni++)
        acc[ms][ni] = __builtin_amdgcn_mfma_f32_16x16x32_bf16(af[ms], bfr[ni], acc[ms][ni], 0,0,0);
  }
  float* op = out + (size_t)blockIdx.y * 64 * ldo;
  #pragma unroll
  for (int ms=0; ms<4; ms++)
    #pragma unroll
    for (int ni=0; ni<4; ni++)
      #pragma unroll
      for (int r=0; r<4; r++){
        int m = ms*16 + l4*4 + r;
        op[(size_t)m*ldo + n0 + ni*16 + l15] = acc[ms][ni][r];
      }
}

// ---------------- K3: fused attention energy, 16x16x32 frags, 2-deep B prefetch ----------------
// 4096 blocks x 256 thr (4 waves). Block: M=64 t x N=256 a (a-quarter), K=1024.
// Wave: M=64 x N=64, acc = 16 tiles x f32x4 = 64 AGPR.
// A: keys f32 -> st regs (chunk-ahead prefetch) -> cvt_pk -> XOR-swizzled LDS (dbuf 2x16KB).
// B: fragment-packed bf16 pk, streamed from L2, 2-step-deep register prefetch.
// XCD map: 4 a-quarters of a key tile adjacent on one XCD; each XCD serves one att.
__global__ __launch_bounds__(256,2) void k_energy(
    const float* __restrict__ enc, const float* __restrict__ bwd,
    const short* __restrict__ pke, const short* __restrict__ pkb,
    const float* __restrict__ qpe, const float* __restrict__ qpb,  // [2][64][1024] K-split partials
    const float* __restrict__ ve, const float* __restrict__ vb,
    float* __restrict__ ep_out){                                   // [att][4][64][512]
  __shared__ short A_s[2][64*128];          // 2 x 16 KB, XOR-swizzled
  __shared__ float ebuf[4][64];

  int wg = blockIdx.x;
  int xcd = wg & 7, idx = wg >> 3;          // idx 0..511
  int qt = idx & 3, rest = idx >> 2;        // a-quarter innermost (same-XCD A reuse)
  int u  = xcd*128 + rest;                  // 0..1023 = (att, b, ttile)
  int att = u >> 9;
  int b   = (u >> 3) & 63;
  int t0  = (u & 7)*64;

  const float* keys = att ? bwd : enc;
  const short* pk   = att ? pkb : pke;
  const float* qp   = att ? qpb : qpe;
  const float* v    = att ? vb  : ve;

  int tid = threadIdx.x, l = tid & 63, w = tid >> 6;
  int l15 = l & 15, l4 = l >> 4;

  // A staging: thread (sr=row, sf=32-float segment); 8 float4 per chunk
  int sr = tid >> 2, sf = tid & 3;
  const float4* ssrc = (const float4*)(keys + ((size_t)(b*TSEQ) + t0 + sr)*1024) + sf*8;
  int sw = (sr & 7) << 4;
  int aw0 = (sf*64 +  0) ^ sw;
  int aw1 = (sf*64 + 16) ^ sw;
  int aw2 = (sf*64 + 32) ^ sw;
  int aw3 = (sf*64 + 48) ^ sw;

  // B fragment pointers: wave's 4 nt-tiles
  const short* pB[4];
  #pragma unroll
  for (int ni=0; ni<4; ni++)
    pB[ni] = pk + ((size_t)(qt*16 + w*4 + ni)*32)*512 + (size_t)l*8;

  f32x4 acc[4][4];
  #pragma unroll
  for (int i=0;i<4;i++)
    #pragma unroll
    for (int j=0;j<4;j++)
      #pragma unroll
      for (int r=0;r<4;r++) acc[i][j][r]=0.f;

  float4 st[8];
  #pragma unroll
  for (int i=0;i<8;i++) st[i] = ssrc[i];                 // A chunk 0
  {
    char* awr = (char*)A_s + sr*256;
    *(bf16x8*)(awr + aw0) = cvt8(st[0], st[1]);
    *(bf16x8*)(awr + aw1) = cvt8(st[2], st[3]);
    *(bf16x8*)(awr + aw2) = cvt8(st[4], st[5]);
    *(bf16x8*)(awr + aw3) = cvt8(st[6], st[7]);
  }
  __syncthreads();
  #pragma unroll
  for (int i=0;i<8;i++) st[i] = ssrc[32 + i];            // A chunk 1

  bf16x8 bfr[2][4];                                      // 2-deep B pipeline
  #pragma unroll
  for (int ni=0; ni<4; ni++) bfr[0][ni] = *(const bf16x8*)(pB[ni]);
  #pragma unroll
  for (int ni=0; ni<4; ni++) bfr[1][ni] = *(const bf16x8*)(pB[ni] + 512);

  for (int c=0; c<8; ++c){
    const char* base = (const char*)A_s + (c&1)*16384;
    #pragma unroll
    for (int ss=0; ss<4; ++ss){
      int s = c*4 + ss;
      bf16x8 af[4];
      #pragma unroll
      for (int ms=0; ms<4; ms++){
        int row = ms*16 + l15;
        af[ms] = *(const bf16x8*)(base + row*256 + ((ss*64 + l4*16) ^ ((row&7)<<4)));
      }
      #pragma unroll
      for (int ms=0; ms<4; ms++)
        #pragma unroll
        for (int ni=0; ni<4; ni++)
          acc[ms][ni] = __builtin_amdgcn_mfma_f32_16x16x32_bf16(af[ms], bfr[ss&1][ni], acc[ms][ni], 0,0,0);
      int sp = (s + 2) & 31;                             // tail wraps: harmless reload
      #pragma unroll
      for (int ni=0; ni<4; ni++)
        bfr[ss&1][ni] = *(const bf16x8*)(pB[ni] + (size_t)sp*512);
    }
    if (c < 7){
      char* dst = (char*)A_s + ((c+1)&1)*16384 + sr*256;  // write-late (T14)
      *(bf16x8*)(dst + aw0) = cvt8(st[0], st[1]);
      *(bf16x8*)(dst + aw1) = cvt8(st[2], st[3]);
      *(bf16x8*)(dst + aw2) = cvt8(st[4], st[5]);
      *(bf16x8*)(dst + aw3) = cvt8(st[6], st[7]);
      if (c < 6){
        #pragma unroll
        for (int i=0;i<8;i++) st[i] = ssrc[(c+2)*32 + i]; // covered by next chunk's MFMA
      }
    }
    __syncthreads();
  }

  // fused epilogue: partial e over this wave's 64 a's
  float qv[4], vv[4];
  #pragma unroll
  for (int ni=0; ni<4; ni++){
    int a = qt*256 + w*64 + ni*16 + l15;
    qv[ni] = qp[(size_t)b*HIDD + a] + qp[65536 + (size_t)b*HIDD + a];
    vv[ni] = v[a];
  }
  float es[16];
  #pragma unroll
  for (int ms=0; ms<4; ms++)
    #pragma unroll
    for (int r=0; r<4; r++){
      float s = 0.f;
      #pragma unroll
      for (int ni=0; ni<4; ni++)
        s += vv[ni]*fast_tanh(qv[ni] + acc[ms][ni][r]);
      es[ms*4+r] = s;
    }
  #pragma unroll
  for (int i=0;i<16;i++){
    float x = es[i];
    x += __shfl_xor(x,1); x += __shfl_xor(x,2);
    x += __shfl_xor(x,4); x += __shfl_xor(x,8);
    es[i] = x;
  }
  if (l15 == 0){
    #pragma unroll
    for (int ms=0; ms<4; ms++)
      #pragma unroll
      for (int r=0; r<4; r++)
        ebuf[w][ms*16 + l4*4 + r] = es[ms*4+r];
  }
  __syncthreads();
  if (tid < 64){
    float s = ebuf[0][tid] + ebuf[1][tid] + ebuf[2][tid] + ebuf[3][tid];
    ep_out[(((size_t)att*4 + qt)*BB + b)*TSEQ + t0 + tid] = s;
  }
}

// ---------------- K4: softmax over T (sums 4 a-quarter partials, applies mask) ----------------
__global__ __launch_bounds__(256) void k_softmax_t(const float* __restrict__ ep,
                                                   const int* __restrict__ mask,
                                                   float* __restrict__ att_e,
                                                   float* __restrict__ att_b){
  int b = blockIdx.x, att = blockIdx.y;
  float* e = (att ? att_b : att_e) + (size_t)b*TSEQ;
  __shared__ float red[8];
  int tid = threadIdx.x, lane = tid & 63, w = tid >> 6;
  float v0 = 0.f, v1 = 0.f;
  #pragma unroll
  for (int i=0;i<4;i++){
    const float* p = ep + (((size_t)att*4 + i)*BB + b)*TSEQ;
    v0 += p[tid]; v1 += p[tid+256];
  }
  if (att==0){
    if (mask[(size_t)b*TSEQ + tid]==0)      v0 = -3.4e38f;
    if (mask[(size_t)b*TSEQ + tid+256]==0)  v1 = -3.4e38f;
  }
  float m = wave_max(fmaxf(v0, v1));
  if (lane==0) red[w] = m;
  __syncthreads();
  m = fmaxf(fmaxf(red[0],red[1]), fmaxf(red[2],red[3]));
  float x0 = __expf(v0-m), x1 = __expf(v1-m);
  float s = wave_sum(x0+x1);
  if (lane==0) red[4+w] = s;
  __syncthreads();
  s = red[4]+red[5]+red[6]+red[7];
  float inv = 1.0f/s;
  e[tid] = x0*inv; e[tid+256] = x1*inv;
}

// ---------------- K5: context = attn @ keys (float4-vectorized) ----------------
__global__ __launch_bounds__(256) void k_ctx(const float* __restrict__ enc,
                                             const float* __restrict__ bwdst,
                                             const float* __restrict__ att_e,
                                             const float* __restrict__ att_b,
                                             float* __restrict__ ctxp){
  int b = blockIdx.x, sel = blockIdx.y, s = blockIdx.z;
  const float4* keys4 = (const float4*)((sel ? bwdst : enc) + ((size_t)b*TSEQ + s*64)*1024);
  const float* att  = (sel ? att_b : att_e) + (size_t)b*TSEQ + s*64;
  int tid = threadIdx.x;
  float ax=0.f, ay=0.f, az=0.f, aw=0.f;
  for (int t=0;t<64;t++){
    float a = att[t];
    float4 kv = keys4[(size_t)t*256 + tid];
    ax += a*kv.x; ay += a*kv.y; az += a*kv.z; aw += a*kv.w;
  }
  float4 o; o.x=ax; o.y=ay; o.z=az; o.w=aw;
  ((float4*)(ctxp + (((size_t)sel*BB + b)*8 + s)*1024))[tid] = o;
}

__global__ __launch_bounds__(256) void k_ctxred(const float* __restrict__ ctxp,
                                                float* __restrict__ ctx_e,
                                                float* __restrict__ ctx_b){
  int id = blockIdx.x*256 + threadIdx.x;
  int sel = id >> 16; int rem = id & 65535; int b = rem >> 10; int d = rem & 1023;
  const float* p = ctxp + (((size_t)sel*BB + b)*8)*1024 + d;
  float s = 0.f;
  #pragma unroll
  for (int i=0;i<8;i++) s += p[i*1024];
  (sel ? ctx_b : ctx_e)[(size_t)b*HIDD + d] = s;
}

// ---------------- K7: LSTM cell (8-slot partial reduce) + bf16 h_new ----------------
__global__ __launch_bounds__(256) void k_lstm(const float* __restrict__ gp,
                                              const float* __restrict__ b_ih,
                                              const float* __restrict__ b_hh,
                                              const float* __restrict__ c_old,
                                              float* __restrict__ out,
                                              short* __restrict__ hb){
  int id = blockIdx.x*256 + threadIdx.x;    // 65536
  int b = id >> 10, j = id & 1023;
  size_t base = (size_t)b*G4;
  float gs[4];
  #pragma unroll
  for (int g=0; g<4; g++){
    int col = g*1024 + j;
    float s = b_ih[col] + b_hh[col];
    #pragma unroll
    for (int k=0;k<8;k++) s += gp[(size_t)k*(64*G4) + base + col];
    gs[g] = s;
  }
  float ig = sigmoid_f(gs[0]);
  float fg = sigmoid_f(gs[1]);
  float gg = tanhf(gs[2]);
  float og = sigmoid_f(gs[3]);
  float cn = fg*c_old[id] + ig*gg;
  float hn = og*tanhf(cn);
  out[(size_t)BB*VSZ + id] = hn;
  out[(size_t)BB*VSZ + (size_t)BB*HIDD + id] = cn;
  hb[id] = f2bfs(hn);
}

// ---------------- K8: vocab logits via MFMA, N=128/block (250 blocks) ----------------
__global__ __launch_bounds__(256) void k_vocab2(const short* __restrict__ hb,
                                                const float* __restrict__ Wp,
                                                const float* __restrict__ bp,
                                                float* __restrict__ out){
  int tid = threadIdx.x, l = tid & 63, w = tid >> 6;
  int l15 = l & 15, l4 = l >> 4;
  int mh = w >> 1;
  int n0 = blockIdx.x*128 + (w&1)*64;
  f32x4 acc[2][4];
  #pragma unroll
  for (int i=0;i<2;i++)
    #pragma unroll
    for (int j=0;j<4;j++)
      #pragma unroll
      for (int r=0;r<4;r++) acc[i][j][r]=0.f;
  for (int d0=0; d0<1024; d0+=32){
    bf16x8 af[2];
    #pragma unroll
    for (int ms=0; ms<2; ms++)
      af[ms] = *(const bf16x8*)(hb + (size_t)(mh*32 + ms*16 + l15)*1024 + d0 + l4*8);
    bf16x8 bfr[4];
    #pragma unroll
    for (int ni=0; ni<4; ni++){
      const float* bpp = Wp + (size_t)(n0 + ni*16 + l15)*1024 + d0 + l4*8;
      float4 f0 = ((const float4*)bpp)[0], f1 = ((const float4*)bpp)[1];
      bfr[ni] = cvt8(f0, f1);
    }
    #pragma unroll
    for (int ms=0; ms<2; ms++)
      #pragma unroll
      for (int ni=0; ni<4; ni++)
        acc[ms][ni] = __builtin_amdgcn_mfma_f32_16x16x32_bf16(af[ms], bfr[ni], acc[ms][ni], 0,0,0);
  }
  #pragma unroll
  for (int ms=0; ms<2; ms++)
    #pragma unroll
    for (int ni=0; ni<4; ni++)
      #pragma unroll
      for (int r=0; r<4; r++){
        int m = mh*32 + ms*16 + l4*4 + r;
        int n = n0 + ni*16 + l15;
        out[(size_t)m*VSZ + n] = acc[ms][ni][r] + bp[n];
      }
}

// ---------------- K9: p_gen + softmax(V), 1024 threads ----------------
__global__ __launch_bounds__(1024) void k_final(const float* __restrict__ ctxe,
                                                const float* __restrict__ tab,
                                                const int* __restrict__ y,
                                                const float* __restrict__ wc,
                                                const float* __restrict__ wsv,
                                                const float* __restrict__ wy,
                                                const float* __restrict__ pgb,
                                                float* __restrict__ out,
                                                float* __restrict__ pgen_ws){
  __shared__ float red[32];
  int b = blockIdx.x, tid = threadIdx.x, lane = tid & 63, w = tid >> 6;
  const float* hn = out + (size_t)BB*VSZ + (size_t)b*HIDD;
  float acc = ctxe[(size_t)b*HIDD + tid]*wc[tid] + hn[tid]*wsv[tid];
  if (tid < 512) acc += tab[(size_t)y[b]*EMBD + tid]*wy[tid];
  acc = wave_sum(acc);
  if (lane==0) red[w] = acc;
  __syncthreads();
  float s0 = pgb[0];
  #pragma unroll
  for (int i=0;i<16;i++) s0 += red[i];
  float pg = sigmoid_f(s0);
  if (tid==0) pgen_ws[b] = pg;
  __syncthreads();

  float* row = out + (size_t)b*VSZ;
  float m = -3.4e38f;
  for (int i=tid;i<VSZ;i+=1024) m = fmaxf(m, row[i]);
  m = wave_max(m);
  if (lane==0) red[w] = m;
  __syncthreads();
  #pragma unroll
  for (int i=0;i<16;i++) m = fmaxf(m, red[i]);
  float s = 0.f;
  for (int i=tid;i<VSZ;i+=1024) s += __expf(row[i]-m);
  s = wave_sum(s);
  if (lane==0) red[16+w] = s;
  __syncthreads();
  float tot = 0.f;
  #pragma unroll
  for (int i=0;i<16;i++) tot += red[16+i];
  float scale = pg / tot;
  for (int i=tid;i<VSZ;i+=1024) row[i] = __expf(row[i]-m)*scale;
}

// ---------------- K10: pointer scatter ----------------
__global__ __launch_bounds__(256) void k_scatter(const int* __restrict__ src_ids,
                                                 const float* __restrict__ att_e,
                                                 const float* __restrict__ pgen_ws,
                                                 float* __restrict__ out){
  int id = blockIdx.x*256 + threadIdx.x;
  int b = id >> 9;
  float pg = pgen_ws[b];
  int sid = src_ids[id];
  float contrib = (1.0f - pg) * att_e[id] * (sid < VSZ ? 1.0f : 0.0f);
  int safe = sid < VSZ-1 ? sid : VSZ-1;
  atomicAdd(&out[(size_t)b*VSZ + safe], contrib);
}

extern "C" void kernel_launch(void* const* d_in, const int* in_sizes, int n_in,
                              void* d_out, int out_size, void* d_ws, size_t ws_size,
                              hipStream_t stream){
  const int*   y     = (const int*)d_in[0];
  const float* h     = (const float*)d_in[1];
  const float* c     = (const float*)d_in[2];
  const float* enc   = (const float*)d_in[3];
  const float* bwd   = (const float*)d_in[4];
  const int*   sids  = (const int*)d_in[5];
  const int*   smask = (const int*)d_in[6];
  const float* tab   = (const float*)d_in[7];
  const float* W_ih  = (const float*)d_in[8];
  const float* W_hh  = (const float*)d_in[9];
  const float* b_ih  = (const float*)d_in[10];
  const float* b_hh  = (const float*)d_in[11];
  const float* Wq_e  = (const float*)d_in[12];
  const float* Wk_e  = (const float*)d_in[13];
  const float* v_e   = (const float*)d_in[14];
  const float* Wq_b  = (const float*)d_in[15];
  const float* Wk_b  = (const float*)d_in[16];
  const float* v_b   = (const float*)d_in[17];
  const float* Wp    = (const float*)d_in[18];
  const float* bp    = (const float*)d_in[19];
  const float* wc    = (const float*)d_in[20];
  const float* wsv   = (const float*)d_in[21];
  const float* wy    = (const float*)d_in[22];
  const float* pgb   = (const float*)d_in[23];
  float* out = (float*)d_out;

  float* W = (float*)d_ws;
  float* ws_qpe  = W; W += 2*BB*HIDD;        // qproj partials (2 K-split slots)
  float* ws_qpb  = W; W += 2*BB*HIDD;
  float* ws_ep   = W; W += 2*8*BB*TSEQ;      // energy partials (uses [2][4][64][512])
  float* ws_atte = W; W += BB*TSEQ;
  float* ws_attb = W; W += BB*TSEQ;
  float* ws_ctxe = W; W += BB*HIDD;
  float* ws_ctxb = W; W += BB*HIDD;
  float* ws_ctxp = W; W += 2*BB*8*1024;      // 1048576
  float* ws_pgen = W; W += 64;
  float* ws_gp   = W; W += 8*BB*G4;          // 2097152 (8 K-split slots)
  short* xb      = (short*)W; W += (BB*3584)/2;
  short* hb      = (short*)W; W += (BB*HIDD)/2;
  short* pk_e    = (short*)W; W += (HIDD*HIDD)/2;   // fragment-order Wk_e bf16
  short* pk_b    = (short*)W; W += (HIDD*HIDD)/2;

  k_pack<<<512, 256, 0, stream>>>(Wk_e, pk_e);
  k_pack<<<512, 256, 0, stream>>>(Wk_b, pk_b);
  k_prep_h<<<32, 256, 0, stream>>>(h, xb);
  k_mm64<<<dim3(4,2,2), 256, 0, stream>>>(
      xb+2560, 3584, Wq_e, 1024, 1024, ws_qpe, 1024,
      xb+2560, 3584, Wq_b, 1024, 1024, ws_qpb, 1024);
  k_energy<<<4096, 256, 0, stream>>>(enc, bwd, pk_e, pk_b,
      ws_qpe, ws_qpb, v_e, v_b, ws_ep);
  k_softmax_t<<<dim3(BB,2), 256, 0, stream>>>(ws_ep, smask, ws_atte, ws_attb);
  k_ctx<<<dim3(BB,2,8), 256, 0, stream>>>(enc, bwd, ws_atte, ws_attb, ws_ctxp);
  k_ctxred<<<512, 256, 0, stream>>>(ws_ctxp, ws_ctxe, ws_ctxb);
  k_prep_x2<<<80, 256, 0, stream>>>(tab, y, ws_ctxe, ws_ctxb, xb);
  k_mm64<<<dim3(16,4,2), 256, 0, stream>>>(
      xb,      3584, W_ih, 2560, 2560, ws_gp,             G4,
      xb+2560, 3584, W_hh, 1024, 1024, ws_gp + 4*BB*G4,   G4);
  k_lstm<<<256, 256, 0, stream>>>(ws_gp, b_ih, b_hh, c, out, hb);
  k_vocab2<<<250, 256, 0, stream>>>(hb, Wp, bp, out);
  k_final<<<BB, 1024, 0, stream>>>(ws_ctxe, tab, y, wc, wsv, wy, pgb, out, ws_pgen);
  k_scatter<<<128, 256, 0, stream>>>(sids, ws_atte, ws_pgen, out);
}

// Round 10
// 391.561 us; speedup vs baseline: 1.3156x; 1.0635x over previous
//
#include <hip/hip_runtime.h>
#include <hip/hip_bf16.h>

#define VSZ   32000
#define EMBD  512
#define HIDD  1024
#define BB    64
#define TSEQ  512
#define G4    4096

typedef short bf16x8 __attribute__((ext_vector_type(8)));
typedef float f32x4  __attribute__((ext_vector_type(4)));

typedef __attribute__((address_space(3))) unsigned       lds_u32_t;
typedef __attribute__((address_space(1))) const unsigned glb_u32_t;
__device__ __forceinline__ void gload16(const void* g, void* l){
  __builtin_amdgcn_global_load_lds((glb_u32_t*)g, (lds_u32_t*)l, 16, 0, 0);
}

__device__ __forceinline__ float sigmoid_f(float x){ return 1.0f/(1.0f+__expf(-x)); }
__device__ __forceinline__ float fast_tanh(float x){
  float e = __expf(2.0f*x);
  return 1.0f - 2.0f*__builtin_amdgcn_rcpf(e + 1.0f);
}
__device__ __forceinline__ short f2bfs(float x){
  unsigned u = __float_as_uint(x);
  unsigned r = (u + 0x7FFFu + ((u>>16)&1u)) >> 16;
  return (short)r;
}
__device__ __forceinline__ float bf2f(short s){
  return __uint_as_float(((unsigned)(unsigned short)s) << 16);
}
// single-instr packed f32x2 -> bf16x2 (RNE), gfx950
__device__ __forceinline__ unsigned cvtpk(float a, float b){
  unsigned r;
  asm("v_cvt_pk_bf16_f32 %0, %1, %2" : "=v"(r) : "v"(a), "v"(b));
  return r;
}
__device__ __forceinline__ bf16x8 cvt8(float4 a, float4 b){
  union { unsigned u[4]; bf16x8 v; } o;
  o.u[0]=cvtpk(a.x,a.y); o.u[1]=cvtpk(a.z,a.w);
  o.u[2]=cvtpk(b.x,b.y); o.u[3]=cvtpk(b.z,b.w);
  return o.v;
}
__device__ __forceinline__ float wave_sum(float x){
  #pragma unroll
  for (int off=32; off>0; off>>=1) x += __shfl_xor(x, off);
  return x;
}
__device__ __forceinline__ float wave_max(float x){
  #pragma unroll
  for (int off=32; off>0; off>>=1) x = fmaxf(x, __shfl_xor(x, off));
  return x;
}

// ---------------- pack Wk -> bf16 row-major, cols pre-XOR-swizzled within 64-chunks ----------------
// pk[a][c] = bf16(Wk[a][(c & ~63) | ((c & 63) ^ ((a&7)*8))])   (verified, round 4)
__global__ __launch_bounds__(256) void k_pack(const float* __restrict__ Wk,
                                              short* __restrict__ dst){
  int id = blockIdx.x*256 + threadIdx.x;   // 131072 = 1024a * 128g
  int a = id >> 7, g = id & 127;
  int gs = (g & ~7) | ((g & 7) ^ (a & 7));
  const float* src = Wk + (size_t)a*1024 + gs*8;
  float4 f0 = ((const float4*)src)[0], f1 = ((const float4*)src)[1];
  *(bf16x8*)(dst + (size_t)id*8) = cvt8(f0, f1);
}

// ---------------- convert keys (enc/bwd) -> bf16, same pre-swizzled layout per row ----------------
// pkeys[att][b*512+t][g] = bf16(keys[b][t][ (g&~7|((g&7)^(t&7)))*8 .. +8 ])
__global__ __launch_bounds__(256) void k_cvtkeys(const float* __restrict__ enc,
                                                 const float* __restrict__ bwd,
                                                 short* __restrict__ dst){
  int att = blockIdx.y;
  const float* src0 = att ? bwd : enc;
  int id = blockIdx.x*256 + threadIdx.x;   // 64b*512t*128g = 4194304
  int g = id & 127, bt = id >> 7;
  int t = bt & 511;
  int gs = (g & ~7) | ((g & 7) ^ (t & 7));
  const float* sp = src0 + (size_t)bt*1024 + gs*8;
  float4 f0 = ((const float4*)sp)[0], f1 = ((const float4*)sp)[1];
  *(bf16x8*)(dst + (((size_t)att*32768 + bt)*128 + g)*8) = cvt8(f0, f1);
}

// ---------------- prep: x_bf16[:,2560:3584] = bf16(h) ----------------
__global__ __launch_bounds__(256) void k_prep_h(const float* __restrict__ h,
                                                short* __restrict__ xb){
  int id = blockIdx.x*256 + threadIdx.x;     // 8192
  int b = id >> 7, d = (id & 127)*8;
  const float4* s = (const float4*)(h + (size_t)b*HIDD + d);
  *(bf16x8*)(xb + (size_t)b*3584 + 2560 + d) = cvt8(s[0], s[1]);
}

// ---------------- prep: x_bf16[:,0:2560] = bf16(emb|ctxe|ctxb), emb gathered ----------------
__global__ __launch_bounds__(256) void k_prep_x2(const float* __restrict__ tab,
                                                 const int* __restrict__ y,
                                                 const float* __restrict__ ctxe,
                                                 const float* __restrict__ ctxb,
                                                 short* __restrict__ xb){
  int id = blockIdx.x*256 + threadIdx.x;     // 20480
  if (id >= 64*320) return;
  int b = id / 320, off = (id % 320)*8;
  const float* src;
  if (off < 512)        src = tab  + (size_t)y[b]*EMBD + off;
  else if (off < 1536)  src = ctxe + (size_t)b*HIDD + (off-512);
  else                  src = ctxb + (size_t)b*HIDD + (off-1536);
  float4 f0 = ((const float4*)src)[0], f1 = ((const float4*)src)[1];
  *(bf16x8*)(xb + (size_t)b*3584 + off) = cvt8(f0, f1);
}

// ---------------- generic M=64 MFMA GEMM with K-split partials ----------------
__global__ __launch_bounds__(256) void k_mm64(
    const short* __restrict__ A0, int lda0, const float* __restrict__ B0, int ldb0, int K0, float* __restrict__ out0, int ldo0,
    const short* __restrict__ A1, int lda1, const float* __restrict__ B1, int ldb1, int K1, float* __restrict__ out1, int ldo1){
  const short* A; const float* B; float* out; int lda, ldb, K, ldo;
  if (blockIdx.z == 0){ A=A0; B=B0; out=out0; lda=lda0; ldb=ldb0; K=K0; ldo=ldo0; }
  else                { A=A1; B=B1; out=out1; lda=lda1; ldb=ldb1; K=K1; ldo=ldo1; }
  int tid = threadIdx.x, l = tid & 63, w = tid >> 6;
  int l15 = l & 15, l4 = l >> 4;
  int n0 = blockIdx.x*256 + w*64;
  int kper = K / gridDim.y;
  int dbeg = blockIdx.y * kper, dend = dbeg + kper;
  f32x4 acc[4][4];
  #pragma unroll
  for (int i=0;i<4;i++)
    #pragma unroll
    for (int j=0;j<4;j++)
      #pragma unroll
      for (int r=0;r<4;r++) acc[i][j][r]=0.f;
  for (int d0=dbeg; d0<dend; d0+=32){
    bf16x8 af[4];
    #pragma unroll
    for (int ms=0; ms<4; ms++)
      af[ms] = *(const bf16x8*)(A + (size_t)(ms*16 + l15)*lda + d0 + l4*8);
    bf16x8 bfr[4];
    #pragma unroll
    for (int ni=0; ni<4; ni++){
      const float* bp = B + (size_t)(n0 + ni*16 + l15)*ldb + d0 + l4*8;
      float4 f0 = ((const float4*)bp)[0], f1 = ((const float4*)bp)[1];
      bfr[ni] = cvt8(f0, f1);
    }
    #pragma unroll
    for (int ms=0; ms<4; ms++)
      #pragma unroll
      for (int ni=0; ni<4; ni++)
        acc[ms][ni] = __builtin_amdgcn_mfma_f32_16x16x32_bf16(af[ms], bfr[ni], acc[ms][ni], 0,0,0);
  }
  float* op = out + (size_t)blockIdx.y * 64 * ldo;
  #pragma unroll
  for (int ms=0; ms<4; ms++)
    #pragma unroll
    for (int ni=0; ni<4; ni++)
      #pragma unroll
      for (int r=0; r<4; r++){
        int m = ms*16 + l4*4 + r;
        op[(size_t)m*ldo + n0 + ni*16 + l15] = acc[ms][ni][r];
      }
}

// ---------------- K3: energy 128x128x1024 GEMM, BOTH operands via global_load_lds ----------------
// 4096 blocks x 256 thr (4 waves 2x2; wave 64x64, acc 64 AGPR). No in-loop VALU conversion.
// A = pre-swizzled bf16 keys tile; B = pre-swizzled bf16 Wk tile. m97 2-barrier loop.
__global__ __launch_bounds__(256,3) void k_energy(
    const short* __restrict__ pkeys,
    const short* __restrict__ pke, const short* __restrict__ pkb,
    const float* __restrict__ qpe, const float* __restrict__ qpb,  // [2][64][1024] partials
    const float* __restrict__ ve, const float* __restrict__ vb,
    float* __restrict__ ep_out){                                   // [att][8][64][512]
  __shared__ short A_s[128*64];       // 16 KB
  __shared__ short B_s[128*64];       // 16 KB
  __shared__ float ebuf[2][128];

  int wg = blockIdx.x;
  int xcd = wg & 7, idx = wg >> 3;
  int tglob = xcd*64 + (idx >> 3);    // 0..511
  int A0 = idx & 7;                   // a-tile innermost -> same-XCD A reuse
  int att = tglob >> 8;
  int tt  = tglob & 255;
  int b = tt >> 2, t0 = (tt & 3)*128;

  const short* pk = att ? pkb : pke;
  const float* qp = att ? qpb : qpe;
  const float* v  = att ? vb  : ve;

  int tid = threadIdx.x, l = tid & 63, w = tid >> 6;
  int l15 = l & 15, l4 = l >> 4;
  int wr = w >> 1, wc = w & 1;

  // gload sources (pre-swizzled layouts; dest = wave-uniform base + lane*16)
  const char* asrc = (const char*)(pkeys + ((size_t)att*32768 + (size_t)b*512)*1024)
                   + (size_t)(t0 + w*32 + (l>>3))*2048 + (l&7)*16;
  const char* bsrc = (const char*)pk + (size_t)(A0*128 + w*32 + (l>>3))*2048 + (l&7)*16;

  f32x4 acc[4][4];
  #pragma unroll
  for (int i=0;i<4;i++)
    #pragma unroll
    for (int j=0;j<4;j++)
      #pragma unroll
      for (int r=0;r<4;r++) acc[i][j][r]=0.f;

  for (int c=0; c<16; ++c){
    if (c) __syncthreads();             // all waves done reading prev chunk
    #pragma unroll
    for (int k=0;k<4;k++)
      gload16(asrc + (size_t)c*128 + (size_t)k*16384, (char*)A_s + w*4096 + k*1024);
    #pragma unroll
    for (int k=0;k<4;k++)
      gload16(bsrc + (size_t)c*128 + (size_t)k*16384, (char*)B_s + w*4096 + k*1024);
    __syncthreads();                    // drains gloads
    #pragma unroll
    for (int ks=0; ks<2; ks++){
      bf16x8 af[4], bf[4];
      #pragma unroll
      for (int ms=0; ms<4; ms++){
        int row = wr*64 + ms*16 + l15;
        af[ms] = *(const bf16x8*)((char*)A_s + row*128 + ((ks*64 + l4*16) ^ ((row&7)<<4)));
      }
      #pragma unroll
      for (int ni=0; ni<4; ni++){
        int row = wc*64 + ni*16 + l15;
        bf[ni] = *(const bf16x8*)((char*)B_s + row*128 + ((ks*64 + l4*16) ^ ((row&7)<<4)));
      }
      #pragma unroll
      for (int ms=0; ms<4; ms++)
        #pragma unroll
        for (int ni=0; ni<4; ni++)
          acc[ms][ni] = __builtin_amdgcn_mfma_f32_16x16x32_bf16(af[ms], bf[ni], acc[ms][ni], 0,0,0);
    }
  }

  // fused epilogue: e_part[t] = sum_a v[a]*tanh(q[a] + P[t][a]) over this block's 128 a's
  float qv[4], vv[4];
  #pragma unroll
  for (int ni=0; ni<4; ni++){
    int a = A0*128 + wc*64 + ni*16 + l15;
    qv[ni] = qp[(size_t)b*HIDD + a] + qp[65536 + (size_t)b*HIDD + a];
    vv[ni] = v[a];
  }
  float es[16];
  #pragma unroll
  for (int ms=0; ms<4; ms++)
    #pragma unroll
    for (int r=0; r<4; r++){
      float s = 0.f;
      #pragma unroll
      for (int ni=0; ni<4; ni++)
        s += vv[ni]*fast_tanh(qv[ni] + acc[ms][ni][r]);
      es[ms*4+r] = s;
    }
  #pragma unroll
  for (int i=0;i<16;i++){
    float x = es[i];
    x += __shfl_xor(x,1); x += __shfl_xor(x,2);
    x += __shfl_xor(x,4); x += __shfl_xor(x,8);
    es[i] = x;
  }
  if (l15 == 0){
    #pragma unroll
    for (int ms=0; ms<4; ms++)
      #pragma unroll
      for (int r=0; r<4; r++)
        ebuf[wc][wr*64 + ms*16 + l4*4 + r] = es[ms*4+r];
  }
  __syncthreads();
  if (tid < 128)
    ep_out[(((size_t)att*8 + A0)*BB + b)*TSEQ + t0 + tid] = ebuf[0][tid] + ebuf[1][tid];
}

// ---------------- K4: softmax over T (sums 8 a-tile partials, applies mask) ----------------
__global__ __launch_bounds__(256) void k_softmax_t(const float* __restrict__ ep,
                                                   const int* __restrict__ mask,
                                                   float* __restrict__ att_e,
                                                   float* __restrict__ att_b){
  int b = blockIdx.x, att = blockIdx.y;
  float* e = (att ? att_b : att_e) + (size_t)b*TSEQ;
  __shared__ float red[8];
  int tid = threadIdx.x, lane = tid & 63, w = tid >> 6;
  float v0 = 0.f, v1 = 0.f;
  #pragma unroll
  for (int i=0;i<8;i++){
    const float* p = ep + (((size_t)att*8 + i)*BB + b)*TSEQ;
    v0 += p[tid]; v1 += p[tid+256];
  }
  if (att==0){
    if (mask[(size_t)b*TSEQ + tid]==0)      v0 = -3.4e38f;
    if (mask[(size_t)b*TSEQ + tid+256]==0)  v1 = -3.4e38f;
  }
  float m = wave_max(fmaxf(v0, v1));
  if (lane==0) red[w] = m;
  __syncthreads();
  m = fmaxf(fmaxf(red[0],red[1]), fmaxf(red[2],red[3]));
  float x0 = __expf(v0-m), x1 = __expf(v1-m);
  float s = wave_sum(x0+x1);
  if (lane==0) red[4+w] = s;
  __syncthreads();
  s = red[4]+red[5]+red[6]+red[7];
  float inv = 1.0f/s;
  e[tid] = x0*inv; e[tid+256] = x1*inv;
}

// ---------------- K5: context = attn @ keys, reading packed bf16 keys ----------------
// block (b, sel, s-tile). thread: g = col-group (8 bf16), th = t-half of 32.
__global__ __launch_bounds__(256) void k_ctx(const short* __restrict__ pkeys,
                                             const float* __restrict__ att_e,
                                             const float* __restrict__ att_b,
                                             float* __restrict__ ctxp){
  int b = blockIdx.x, sel = blockIdx.y, s = blockIdx.z;
  const short* base = pkeys + (((size_t)sel*32768) + (size_t)b*512 + s*64)*1024;
  const float* att  = (sel ? att_b : att_e) + (size_t)b*TSEQ + s*64;
  int g = threadIdx.x & 127, th = threadIdx.x >> 7;
  const short* rp = base + (size_t)th*32*1024;
  float acc[8];
  #pragma unroll
  for (int j=0;j<8;j++) acc[j]=0.f;
  for (int t=0;t<32;t++){
    float a = att[th*32 + t];
    int gg = (g & ~7) | ((g & 7) ^ (t & 7));   // (th*32+t)&7 == t&7
    bf16x8 kv = *(const bf16x8*)(rp + (size_t)t*1024 + gg*8);
    #pragma unroll
    for (int j=0;j<8;j++) acc[j] += a*bf2f(kv[j]);
  }
  float* o = ctxp + ((((size_t)sel*BB + b)*16) + s*2 + th)*1024 + g*8;
  float4 o0, o1;
  o0.x=acc[0]; o0.y=acc[1]; o0.z=acc[2]; o0.w=acc[3];
  o1.x=acc[4]; o1.y=acc[5]; o1.z=acc[6]; o1.w=acc[7];
  ((float4*)o)[0] = o0; ((float4*)o)[1] = o1;
}

__global__ __launch_bounds__(256) void k_ctxred(const float* __restrict__ ctxp,
                                                float* __restrict__ ctx_e,
                                                float* __restrict__ ctx_b){
  int id = blockIdx.x*256 + threadIdx.x;
  int sel = id >> 16; int rem = id & 65535; int b = rem >> 10; int d = rem & 1023;
  const float* p = ctxp + (((size_t)sel*BB + b)*16)*1024 + d;
  float s = 0.f;
  #pragma unroll
  for (int i=0;i<16;i++) s += p[i*1024];
  (sel ? ctx_b : ctx_e)[(size_t)b*HIDD + d] = s;
}

// ---------------- K7: LSTM cell (8-slot partial reduce) + bf16 h_new ----------------
__global__ __launch_bounds__(256) void k_lstm(const float* __restrict__ gp,
                                              const float* __restrict__ b_ih,
                                              const float* __restrict__ b_hh,
                                              const float* __restrict__ c_old,
                                              float* __restrict__ out,
                                              short* __restrict__ hb){
  int id = blockIdx.x*256 + threadIdx.x;    // 65536
  int b = id >> 10, j = id & 1023;
  size_t base = (size_t)b*G4;
  float gs[4];
  #pragma unroll
  for (int g=0; g<4; g++){
    int col = g*1024 + j;
    float s = b_ih[col] + b_hh[col];
    #pragma unroll
    for (int k=0;k<8;k++) s += gp[(size_t)k*(64*G4) + base + col];
    gs[g] = s;
  }
  float ig = sigmoid_f(gs[0]);
  float fg = sigmoid_f(gs[1]);
  float gg = tanhf(gs[2]);
  float og = sigmoid_f(gs[3]);
  float cn = fg*c_old[id] + ig*gg;
  float hn = og*tanhf(cn);
  out[(size_t)BB*VSZ + id] = hn;
  out[(size_t)BB*VSZ + (size_t)BB*HIDD + id] = cn;
  hb[id] = f2bfs(hn);
}

// ---------------- K8: vocab logits via MFMA, N=128/block (250 blocks) ----------------
__global__ __launch_bounds__(256) void k_vocab2(const short* __restrict__ hb,
                                                const float* __restrict__ Wp,
                                                const float* __restrict__ bp,
                                                float* __restrict__ out){
  int tid = threadIdx.x, l = tid & 63, w = tid >> 6;
  int l15 = l & 15, l4 = l >> 4;
  int mh = w >> 1;
  int n0 = blockIdx.x*128 + (w&1)*64;
  f32x4 acc[2][4];
  #pragma unroll
  for (int i=0;i<2;i++)
    #pragma unroll
    for (int j=0;j<4;j++)
      #pragma unroll
      for (int r=0;r<4;r++) acc[i][j][r]=0.f;
  for (int d0=0; d0<1024; d0+=32){
    bf16x8 af[2];
    #pragma unroll
    for (int ms=0; ms<2; ms++)
      af[ms] = *(const bf16x8*)(hb + (size_t)(mh*32 + ms*16 + l15)*1024 + d0 + l4*8);
    bf16x8 bfr[4];
    #pragma unroll
    for (int ni=0; ni<4; ni++){
      const float* bpp = Wp + (size_t)(n0 + ni*16 + l15)*1024 + d0 + l4*8;
      float4 f0 = ((const float4*)bpp)[0], f1 = ((const float4*)bpp)[1];
      bfr[ni] = cvt8(f0, f1);
    }
    #pragma unroll
    for (int ms=0; ms<2; ms++)
      #pragma unroll
      for (int ni=0; ni<4; ni++)
        acc[ms][ni] = __builtin_amdgcn_mfma_f32_16x16x32_bf16(af[ms], bfr[ni], acc[ms][ni], 0,0,0);
  }
  #pragma unroll
  for (int ms=0; ms<2; ms++)
    #pragma unroll
    for (int ni=0; ni<4; ni++)
      #pragma unroll
      for (int r=0; r<4; r++){
        int m = mh*32 + ms*16 + l4*4 + r;
        int n = n0 + ni*16 + l15;
        out[(size_t)m*VSZ + n] = acc[ms][ni][r] + bp[n];
      }
}

// ---------------- K9: p_gen + softmax(V), 1024 threads ----------------
__global__ __launch_bounds__(1024) void k_final(const float* __restrict__ ctxe,
                                                const float* __restrict__ tab,
                                                const int* __restrict__ y,
                                                const float* __restrict__ wc,
                                                const float* __restrict__ wsv,
                                                const float* __restrict__ wy,
                                                const float* __restrict__ pgb,
                                                float* __restrict__ out,
                                                float* __restrict__ pgen_ws){
  __shared__ float red[32];
  int b = blockIdx.x, tid = threadIdx.x, lane = tid & 63, w = tid >> 6;
  const float* hn = out + (size_t)BB*VSZ + (size_t)b*HIDD;
  float acc = ctxe[(size_t)b*HIDD + tid]*wc[tid] + hn[tid]*wsv[tid];
  if (tid < 512) acc += tab[(size_t)y[b]*EMBD + tid]*wy[tid];
  acc = wave_sum(acc);
  if (lane==0) red[w] = acc;
  __syncthreads();
  float s0 = pgb[0];
  #pragma unroll
  for (int i=0;i<16;i++) s0 += red[i];
  float pg = sigmoid_f(s0);
  if (tid==0) pgen_ws[b] = pg;
  __syncthreads();

  float* row = out + (size_t)b*VSZ;
  float m = -3.4e38f;
  for (int i=tid;i<VSZ;i+=1024) m = fmaxf(m, row[i]);
  m = wave_max(m);
  if (lane==0) red[w] = m;
  __syncthreads();
  #pragma unroll
  for (int i=0;i<16;i++) m = fmaxf(m, red[i]);
  float s = 0.f;
  for (int i=tid;i<VSZ;i+=1024) s += __expf(row[i]-m);
  s = wave_sum(s);
  if (lane==0) red[16+w] = s;
  __syncthreads();
  float tot = 0.f;
  #pragma unroll
  for (int i=0;i<16;i++) tot += red[16+i];
  float scale = pg / tot;
  for (int i=tid;i<VSZ;i+=1024) row[i] = __expf(row[i]-m)*scale;
}

// ---------------- K10: pointer scatter ----------------
__global__ __launch_bounds__(256) void k_scatter(const int* __restrict__ src_ids,
                                                 const float* __restrict__ att_e,
                                                 const float* __restrict__ pgen_ws,
                                                 float* __restrict__ out){
  int id = blockIdx.x*256 + threadIdx.x;
  int b = id >> 9;
  float pg = pgen_ws[b];
  int sid = src_ids[id];
  float contrib = (1.0f - pg) * att_e[id] * (sid < VSZ ? 1.0f : 0.0f);
  int safe = sid < VSZ-1 ? sid : VSZ-1;
  atomicAdd(&out[(size_t)b*VSZ + safe], contrib);
}

extern "C" void kernel_launch(void* const* d_in, const int* in_sizes, int n_in,
                              void* d_out, int out_size, void* d_ws, size_t ws_size,
                              hipStream_t stream){
  const int*   y     = (const int*)d_in[0];
  const float* h     = (const float*)d_in[1];
  const float* c     = (const float*)d_in[2];
  const float* enc   = (const float*)d_in[3];
  const float* bwd   = (const float*)d_in[4];
  const int*   sids  = (const int*)d_in[5];
  const int*   smask = (const int*)d_in[6];
  const float* tab   = (const float*)d_in[7];
  const float* W_ih  = (const float*)d_in[8];
  const float* W_hh  = (const float*)d_in[9];
  const float* b_ih  = (const float*)d_in[10];
  const float* b_hh  = (const float*)d_in[11];
  const float* Wq_e  = (const float*)d_in[12];
  const float* Wk_e  = (const float*)d_in[13];
  const float* v_e   = (const float*)d_in[14];
  const float* Wq_b  = (const float*)d_in[15];
  const float* Wk_b  = (const float*)d_in[16];
  const float* v_b   = (const float*)d_in[17];
  const float* Wp    = (const float*)d_in[18];
  const float* bp    = (const float*)d_in[19];
  const float* wc    = (const float*)d_in[20];
  const float* wsv   = (const float*)d_in[21];
  const float* wy    = (const float*)d_in[22];
  const float* pgb   = (const float*)d_in[23];
  float* out = (float*)d_out;

  float* W = (float*)d_ws;
  float* ws_qpe  = W; W += 2*BB*HIDD;        // qproj partials (2 K-split slots)
  float* ws_qpb  = W; W += 2*BB*HIDD;
  float* ws_ep   = W; W += 2*8*BB*TSEQ;      // energy partials [att][8][b][t]
  float* ws_atte = W; W += BB*TSEQ;
  float* ws_attb = W; W += BB*TSEQ;
  float* ws_ctxe = W; W += BB*HIDD;
  float* ws_ctxb = W; W += BB*HIDD;
  float* ws_ctxp = W; W += 2*BB*16*1024;     // 2097152 (16 slots)
  float* ws_pgen = W; W += 64;
  float* ws_gp   = W; W += 8*BB*G4;          // 2097152 (8 K-split slots)
  short* xb      = (short*)W; W += (BB*3584)/2;
  short* hb      = (short*)W; W += (BB*HIDD)/2;
  short* pk_e    = (short*)W; W += (HIDD*HIDD)/2;   // packed+swizzled Wk_e bf16
  short* pk_b    = (short*)W; W += (HIDD*HIDD)/2;
  short* pkeys   = (short*)W; W += (2*BB*TSEQ*HIDD)/2;  // 128 MB packed bf16 keys

  k_pack<<<512, 256, 0, stream>>>(Wk_e, pk_e);
  k_pack<<<512, 256, 0, stream>>>(Wk_b, pk_b);
  k_cvtkeys<<<dim3(16384,2), 256, 0, stream>>>(enc, bwd, pkeys);
  k_prep_h<<<32, 256, 0, stream>>>(h, xb);
  k_mm64<<<dim3(4,2,2), 256, 0, stream>>>(
      xb+2560, 3584, Wq_e, 1024, 1024, ws_qpe, 1024,
      xb+2560, 3584, Wq_b, 1024, 1024, ws_qpb, 1024);
  k_energy<<<4096, 256, 0, stream>>>(pkeys, pk_e, pk_b,
      ws_qpe, ws_qpb, v_e, v_b, ws_ep);
  k_softmax_t<<<dim3(BB,2), 256, 0, stream>>>(ws_ep, smask, ws_atte, ws_attb);
  k_ctx<<<dim3(BB,2,8), 256, 0, stream>>>(pkeys, ws_atte, ws_attb, ws_ctxp);
  k_ctxred<<<512, 256, 0, stream>>>(ws_ctxp, ws_ctxe, ws_ctxb);
  k_prep_x2<<<80, 256, 0, stream>>>(tab, y, ws_ctxe, ws_ctxb, xb);
  k_mm64<<<dim3(16,4,2), 256, 0, stream>>>(
      xb,      3584, W_ih, 2560, 2560, ws_gp,             G4,
      xb+2560, 3584, W_hh, 1024, 1024, ws_gp + 4*BB*G4,   G4);
  k_lstm<<<256, 256, 0, stream>>>(ws_gp, b_ih, b_hh, c, out, hb);
  k_vocab2<<<250, 256, 0, stream>>>(hb, Wp, bp, out);
  k_final<<<BB, 1024, 0, stream>>>(ws_ctxe, tab, y, wc, wsv, wy, pgb, out, ws_pgen);
  k_scatter<<<128, 256, 0, stream>>>(sids, ws_atte, ws_pgen, out);
}

// Round 11
// 387.362 us; speedup vs baseline: 1.3299x; 1.0108x over previous
//
#include <hip/hip_runtime.h>
#include <hip/hip_bf16.h>

#define VSZ   32000
#define EMBD  512
#define HIDD  1024
#define BB    64
#define TSEQ  512
#define G4    4096

typedef short bf16x8 __attribute__((ext_vector_type(8)));
typedef float f32x4  __attribute__((ext_vector_type(4)));

typedef __attribute__((address_space(3))) unsigned       lds_u32_t;
typedef __attribute__((address_space(1))) const unsigned glb_u32_t;
__device__ __forceinline__ void gload16(const void* g, void* l){
  __builtin_amdgcn_global_load_lds((glb_u32_t*)g, (lds_u32_t*)l, 16, 0, 0);
}

__device__ __forceinline__ float sigmoid_f(float x){ return 1.0f/(1.0f+__expf(-x)); }
__device__ __forceinline__ float fast_tanh(float x){
  float e = __expf(2.0f*x);
  return 1.0f - 2.0f*__builtin_amdgcn_rcpf(e + 1.0f);
}
__device__ __forceinline__ short f2bfs(float x){
  unsigned u = __float_as_uint(x);
  unsigned r = (u + 0x7FFFu + ((u>>16)&1u)) >> 16;
  return (short)r;
}
__device__ __forceinline__ float bf2f(short s){
  return __uint_as_float(((unsigned)(unsigned short)s) << 16);
}
// single-instr packed f32x2 -> bf16x2 (RNE), gfx950
__device__ __forceinline__ unsigned cvtpk(float a, float b){
  unsigned r;
  asm("v_cvt_pk_bf16_f32 %0, %1, %2" : "=v"(r) : "v"(a), "v"(b));
  return r;
}
__device__ __forceinline__ bf16x8 cvt8(float4 a, float4 b){
  union { unsigned u[4]; bf16x8 v; } o;
  o.u[0]=cvtpk(a.x,a.y); o.u[1]=cvtpk(a.z,a.w);
  o.u[2]=cvtpk(b.x,b.y); o.u[3]=cvtpk(b.z,b.w);
  return o.v;
}
__device__ __forceinline__ float wave_sum(float x){
  #pragma unroll
  for (int off=32; off>0; off>>=1) x += __shfl_xor(x, off);
  return x;
}
__device__ __forceinline__ float wave_max(float x){
  #pragma unroll
  for (int off=32; off>0; off>>=1) x = fmaxf(x, __shfl_xor(x, off));
  return x;
}

// ---------------- merged prep: pack Wk_e/Wk_b + cvt keys + prep_h, one launch ----------------
// blocks [0,512): pack Wk_e; [512,1024): pack Wk_b;
// blocks [1024,33792): cvtkeys (16384 per att); blocks [33792,33824): prep_h.
// pack:   pk[a][c] = bf16(Wk[a][(c&~63)|((c&63)^((a&7)*8))])        (verified r4)
// cvtkeys: pkeys[att][bt][g] = bf16(keys[bt][(g&~7|((g&7)^(t&7)))*8..]) (verified r10)
__global__ __launch_bounds__(256) void k_prep_all(
    const float* __restrict__ Wk_e, const float* __restrict__ Wk_b,
    const float* __restrict__ enc,  const float* __restrict__ bwd,
    const float* __restrict__ h,
    short* __restrict__ pk_e, short* __restrict__ pk_b,
    short* __restrict__ pkeys, short* __restrict__ xb){
  int bid = blockIdx.x;
  if (bid < 1024){
    const float* Wk = (bid < 512) ? Wk_e : Wk_b;
    short* dst      = (bid < 512) ? pk_e : pk_b;
    int id = (bid & 511)*256 + threadIdx.x;   // 131072 = 1024a * 128g
    int a = id >> 7, g = id & 127;
    int gs = (g & ~7) | ((g & 7) ^ (a & 7));
    const float* src = Wk + (size_t)a*1024 + gs*8;
    float4 f0 = ((const float4*)src)[0], f1 = ((const float4*)src)[1];
    *(bf16x8*)(dst + (size_t)id*8) = cvt8(f0, f1);
  } else if (bid < 33792){
    int r = bid - 1024;                       // 0..32767
    int att = r >> 14;
    const float* src0 = att ? bwd : enc;
    int id = (r & 16383)*256 + threadIdx.x;   // 4194304 = 32768bt * 128g
    int g = id & 127, bt = id >> 7;
    int t = bt & 511;
    int gs = (g & ~7) | ((g & 7) ^ (t & 7));
    const float* sp = src0 + (size_t)bt*1024 + gs*8;
    float4 f0 = ((const float4*)sp)[0], f1 = ((const float4*)sp)[1];
    *(bf16x8*)(pkeys + (((size_t)att*32768 + bt)*128 + g)*8) = cvt8(f0, f1);
  } else {
    int id = (bid - 33792)*256 + threadIdx.x; // 8192
    int b = id >> 7, d = (id & 127)*8;
    const float4* s = (const float4*)(h + (size_t)b*HIDD + d);
    *(bf16x8*)(xb + (size_t)b*3584 + 2560 + d) = cvt8(s[0], s[1]);
  }
}

// ---------------- prep: x_bf16[:,0:2560] = bf16(emb|ctxe|ctxb), emb gathered ----------------
__global__ __launch_bounds__(256) void k_prep_x2(const float* __restrict__ tab,
                                                 const int* __restrict__ y,
                                                 const float* __restrict__ ctxe,
                                                 const float* __restrict__ ctxb,
                                                 short* __restrict__ xb){
  int id = blockIdx.x*256 + threadIdx.x;     // 20480
  if (id >= 64*320) return;
  int b = id / 320, off = (id % 320)*8;
  const float* src;
  if (off < 512)        src = tab  + (size_t)y[b]*EMBD + off;
  else if (off < 1536)  src = ctxe + (size_t)b*HIDD + (off-512);
  else                  src = ctxb + (size_t)b*HIDD + (off-1536);
  float4 f0 = ((const float4*)src)[0], f1 = ((const float4*)src)[1];
  *(bf16x8*)(xb + (size_t)b*3584 + off) = cvt8(f0, f1);
}

// ---------------- generic M=64 MFMA GEMM with K-split partials ----------------
__global__ __launch_bounds__(256) void k_mm64(
    const short* __restrict__ A0, int lda0, const float* __restrict__ B0, int ldb0, int K0, float* __restrict__ out0, int ldo0,
    const short* __restrict__ A1, int lda1, const float* __restrict__ B1, int ldb1, int K1, float* __restrict__ out1, int ldo1){
  const short* A; const float* B; float* out; int lda, ldb, K, ldo;
  if (blockIdx.z == 0){ A=A0; B=B0; out=out0; lda=lda0; ldb=ldb0; K=K0; ldo=ldo0; }
  else                { A=A1; B=B1; out=out1; lda=lda1; ldb=ldb1; K=K1; ldo=ldo1; }
  int tid = threadIdx.x, l = tid & 63, w = tid >> 6;
  int l15 = l & 15, l4 = l >> 4;
  int n0 = blockIdx.x*256 + w*64;
  int kper = K / gridDim.y;
  int dbeg = blockIdx.y * kper, dend = dbeg + kper;
  f32x4 acc[4][4];
  #pragma unroll
  for (int i=0;i<4;i++)
    #pragma unroll
    for (int j=0;j<4;j++)
      #pragma unroll
      for (int r=0;r<4;r++) acc[i][j][r]=0.f;
  for (int d0=dbeg; d0<dend; d0+=32){
    bf16x8 af[4];
    #pragma unroll
    for (int ms=0; ms<4; ms++)
      af[ms] = *(const bf16x8*)(A + (size_t)(ms*16 + l15)*lda + d0 + l4*8);
    bf16x8 bfr[4];
    #pragma unroll
    for (int ni=0; ni<4; ni++){
      const float* bp = B + (size_t)(n0 + ni*16 + l15)*ldb + d0 + l4*8;
      float4 f0 = ((const float4*)bp)[0], f1 = ((const float4*)bp)[1];
      bfr[ni] = cvt8(f0, f1);
    }
    #pragma unroll
    for (int ms=0; ms<4; ms++)
      #pragma unroll
      for (int ni=0; ni<4; ni++)
        acc[ms][ni] = __builtin_amdgcn_mfma_f32_16x16x32_bf16(af[ms], bfr[ni], acc[ms][ni], 0,0,0);
  }
  float* op = out + (size_t)blockIdx.y * 64 * ldo;
  #pragma unroll
  for (int ms=0; ms<4; ms++)
    #pragma unroll
    for (int ni=0; ni<4; ni++)
      #pragma unroll
      for (int r=0; r<4; r++){
        int m = ms*16 + l4*4 + r;
        op[(size_t)m*ldo + n0 + ni*16 + l15] = acc[ms][ni][r];
      }
}

// ---------------- K3: energy 128x128x1024 GEMM, BOTH operands via global_load_lds ----------------
// (unchanged from round 10: 172 us, MfmaUtil 35%, conflicts 0)
__global__ __launch_bounds__(256,3) void k_energy(
    const short* __restrict__ pkeys,
    const short* __restrict__ pke, const short* __restrict__ pkb,
    const float* __restrict__ qpe, const float* __restrict__ qpb,
    const float* __restrict__ ve, const float* __restrict__ vb,
    float* __restrict__ ep_out){                                   // [att][8][64][512]
  __shared__ short A_s[128*64];
  __shared__ short B_s[128*64];
  __shared__ float ebuf[2][128];

  int wg = blockIdx.x;
  int xcd = wg & 7, idx = wg >> 3;
  int tglob = xcd*64 + (idx >> 3);
  int A0 = idx & 7;
  int att = tglob >> 8;
  int tt  = tglob & 255;
  int b = tt >> 2, t0 = (tt & 3)*128;

  const short* pk = att ? pkb : pke;
  const float* qp = att ? qpb : qpe;
  const float* v  = att ? vb  : ve;

  int tid = threadIdx.x, l = tid & 63, w = tid >> 6;
  int l15 = l & 15, l4 = l >> 4;
  int wr = w >> 1, wc = w & 1;

  const char* asrc = (const char*)(pkeys + ((size_t)att*32768 + (size_t)b*512)*1024)
                   + (size_t)(t0 + w*32 + (l>>3))*2048 + (l&7)*16;
  const char* bsrc = (const char*)pk + (size_t)(A0*128 + w*32 + (l>>3))*2048 + (l&7)*16;

  f32x4 acc[4][4];
  #pragma unroll
  for (int i=0;i<4;i++)
    #pragma unroll
    for (int j=0;j<4;j++)
      #pragma unroll
      for (int r=0;r<4;r++) acc[i][j][r]=0.f;

  for (int c=0; c<16; ++c){
    if (c) __syncthreads();
    #pragma unroll
    for (int k=0;k<4;k++)
      gload16(asrc + (size_t)c*128 + (size_t)k*16384, (char*)A_s + w*4096 + k*1024);
    #pragma unroll
    for (int k=0;k<4;k++)
      gload16(bsrc + (size_t)c*128 + (size_t)k*16384, (char*)B_s + w*4096 + k*1024);
    __syncthreads();
    #pragma unroll
    for (int ks=0; ks<2; ks++){
      bf16x8 af[4], bf[4];
      #pragma unroll
      for (int ms=0; ms<4; ms++){
        int row = wr*64 + ms*16 + l15;
        af[ms] = *(const bf16x8*)((char*)A_s + row*128 + ((ks*64 + l4*16) ^ ((row&7)<<4)));
      }
      #pragma unroll
      for (int ni=0; ni<4; ni++){
        int row = wc*64 + ni*16 + l15;
        bf[ni] = *(const bf16x8*)((char*)B_s + row*128 + ((ks*64 + l4*16) ^ ((row&7)<<4)));
      }
      #pragma unroll
      for (int ms=0; ms<4; ms++)
        #pragma unroll
        for (int ni=0; ni<4; ni++)
          acc[ms][ni] = __builtin_amdgcn_mfma_f32_16x16x32_bf16(af[ms], bf[ni], acc[ms][ni], 0,0,0);
    }
  }

  float qv[4], vv[4];
  #pragma unroll
  for (int ni=0; ni<4; ni++){
    int a = A0*128 + wc*64 + ni*16 + l15;
    qv[ni] = qp[(size_t)b*HIDD + a] + qp[65536 + (size_t)b*HIDD + a];
    vv[ni] = v[a];
  }
  float es[16];
  #pragma unroll
  for (int ms=0; ms<4; ms++)
    #pragma unroll
    for (int r=0; r<4; r++){
      float s = 0.f;
      #pragma unroll
      for (int ni=0; ni<4; ni++)
        s += vv[ni]*fast_tanh(qv[ni] + acc[ms][ni][r]);
      es[ms*4+r] = s;
    }
  #pragma unroll
  for (int i=0;i<16;i++){
    float x = es[i];
    x += __shfl_xor(x,1); x += __shfl_xor(x,2);
    x += __shfl_xor(x,4); x += __shfl_xor(x,8);
    es[i] = x;
  }
  if (l15 == 0){
    #pragma unroll
    for (int ms=0; ms<4; ms++)
      #pragma unroll
      for (int r=0; r<4; r++)
        ebuf[wc][wr*64 + ms*16 + l4*4 + r] = es[ms*4+r];
  }
  __syncthreads();
  if (tid < 128)
    ep_out[(((size_t)att*8 + A0)*BB + b)*TSEQ + t0 + tid] = ebuf[0][tid] + ebuf[1][tid];
}

// ---------------- K4: softmax over T (sums 8 a-tile partials, applies mask) ----------------
__global__ __launch_bounds__(256) void k_softmax_t(const float* __restrict__ ep,
                                                   const int* __restrict__ mask,
                                                   float* __restrict__ att_e,
                                                   float* __restrict__ att_b){
  int b = blockIdx.x, att = blockIdx.y;
  float* e = (att ? att_b : att_e) + (size_t)b*TSEQ;
  __shared__ float red[8];
  int tid = threadIdx.x, lane = tid & 63, w = tid >> 6;
  float v0 = 0.f, v1 = 0.f;
  #pragma unroll
  for (int i=0;i<8;i++){
    const float* p = ep + (((size_t)att*8 + i)*BB + b)*TSEQ;
    v0 += p[tid]; v1 += p[tid+256];
  }
  if (att==0){
    if (mask[(size_t)b*TSEQ + tid]==0)      v0 = -3.4e38f;
    if (mask[(size_t)b*TSEQ + tid+256]==0)  v1 = -3.4e38f;
  }
  float m = wave_max(fmaxf(v0, v1));
  if (lane==0) red[w] = m;
  __syncthreads();
  m = fmaxf(fmaxf(red[0],red[1]), fmaxf(red[2],red[3]));
  float x0 = __expf(v0-m), x1 = __expf(v1-m);
  float s = wave_sum(x0+x1);
  if (lane==0) red[4+w] = s;
  __syncthreads();
  s = red[4]+red[5]+red[6]+red[7];
  float inv = 1.0f/s;
  e[tid] = x0*inv; e[tid+256] = x1*inv;
}

// ---------------- K5: context = attn @ keys, reading packed bf16 keys ----------------
__global__ __launch_bounds__(256) void k_ctx(const short* __restrict__ pkeys,
                                             const float* __restrict__ att_e,
                                             const float* __restrict__ att_b,
                                             float* __restrict__ ctxp){
  int b = blockIdx.x, sel = blockIdx.y, s = blockIdx.z;
  const short* base = pkeys + (((size_t)sel*32768) + (size_t)b*512 + s*64)*1024;
  const float* att  = (sel ? att_b : att_e) + (size_t)b*TSEQ + s*64;
  int g = threadIdx.x & 127, th = threadIdx.x >> 7;
  const short* rp = base + (size_t)th*32*1024;
  float acc[8];
  #pragma unroll
  for (int j=0;j<8;j++) acc[j]=0.f;
  for (int t=0;t<32;t++){
    float a = att[th*32 + t];
    int gg = (g & ~7) | ((g & 7) ^ (t & 7));
    bf16x8 kv = *(const bf16x8*)(rp + (size_t)t*1024 + gg*8);
    #pragma unroll
    for (int j=0;j<8;j++) acc[j] += a*bf2f(kv[j]);
  }
  float* o = ctxp + ((((size_t)sel*BB + b)*16) + s*2 + th)*1024 + g*8;
  float4 o0, o1;
  o0.x=acc[0]; o0.y=acc[1]; o0.z=acc[2]; o0.w=acc[3];
  o1.x=acc[4]; o1.y=acc[5]; o1.z=acc[6]; o1.w=acc[7];
  ((float4*)o)[0] = o0; ((float4*)o)[1] = o1;
}

__global__ __launch_bounds__(256) void k_ctxred(const float* __restrict__ ctxp,
                                                float* __restrict__ ctx_e,
                                                float* __restrict__ ctx_b){
  int id = blockIdx.x*256 + threadIdx.x;
  int sel = id >> 16; int rem = id & 65535; int b = rem >> 10; int d = rem & 1023;
  const float* p = ctxp + (((size_t)sel*BB + b)*16)*1024 + d;
  float s = 0.f;
  #pragma unroll
  for (int i=0;i<16;i++) s += p[i*1024];
  (sel ? ctx_b : ctx_e)[(size_t)b*HIDD + d] = s;
}

// ---------------- K7: LSTM cell (8-slot partial reduce) + bf16 h_new ----------------
__global__ __launch_bounds__(256) void k_lstm(const float* __restrict__ gp,
                                              const float* __restrict__ b_ih,
                                              const float* __restrict__ b_hh,
                                              const float* __restrict__ c_old,
                                              float* __restrict__ out,
                                              short* __restrict__ hb){
  int id = blockIdx.x*256 + threadIdx.x;    // 65536
  int b = id >> 10, j = id & 1023;
  size_t base = (size_t)b*G4;
  float gs[4];
  #pragma unroll
  for (int g=0; g<4; g++){
    int col = g*1024 + j;
    float s = b_ih[col] + b_hh[col];
    #pragma unroll
    for (int k=0;k<8;k++) s += gp[(size_t)k*(64*G4) + base + col];
    gs[g] = s;
  }
  float ig = sigmoid_f(gs[0]);
  float fg = sigmoid_f(gs[1]);
  float gg = tanhf(gs[2]);
  float og = sigmoid_f(gs[3]);
  float cn = fg*c_old[id] + ig*gg;
  float hn = og*tanhf(cn);
  out[(size_t)BB*VSZ + id] = hn;
  out[(size_t)BB*VSZ + (size_t)BB*HIDD + id] = cn;
  hb[id] = f2bfs(hn);
}

// ---------------- K8: vocab logits via MFMA, N=128/block (250 blocks) ----------------
__global__ __launch_bounds__(256) void k_vocab2(const short* __restrict__ hb,
                                                const float* __restrict__ Wp,
                                                const float* __restrict__ bp,
                                                float* __restrict__ out){
  int tid = threadIdx.x, l = tid & 63, w = tid >> 6;
  int l15 = l & 15, l4 = l >> 4;
  int mh = w >> 1;
  int n0 = blockIdx.x*128 + (w&1)*64;
  f32x4 acc[2][4];
  #pragma unroll
  for (int i=0;i<2;i++)
    #pragma unroll
    for (int j=0;j<4;j++)
      #pragma unroll
      for (int r=0;r<4;r++) acc[i][j][r]=0.f;
  for (int d0=0; d0<1024; d0+=32){
    bf16x8 af[2];
    #pragma unroll
    for (int ms=0; ms<2; ms++)
      af[ms] = *(const bf16x8*)(hb + (size_t)(mh*32 + ms*16 + l15)*1024 + d0 + l4*8);
    bf16x8 bfr[4];
    #pragma unroll
    for (int ni=0; ni<4; ni++){
      const float* bpp = Wp + (size_t)(n0 + ni*16 + l15)*1024 + d0 + l4*8;
      float4 f0 = ((const float4*)bpp)[0], f1 = ((const float4*)bpp)[1];
      bfr[ni] = cvt8(f0, f1);
    }
    #pragma unroll
    for (int ms=0; ms<2; ms++)
      #pragma unroll
      for (int ni=0; ni<4; ni++)
        acc[ms][ni] = __builtin_amdgcn_mfma_f32_16x16x32_bf16(af[ms], bfr[ni], acc[ms][ni], 0,0,0);
  }
  #pragma unroll
  for (int ms=0; ms<2; ms++)
    #pragma unroll
    for (int ni=0; ni<4; ni++)
      #pragma unroll
      for (int r=0; r<4; r++){
        int m = mh*32 + ms*16 + l4*4 + r;
        int n = n0 + ni*16 + l15;
        out[(size_t)m*VSZ + n] = acc[ms][ni][r] + bp[n];
      }
}

// ---------------- K9a: p_gen ----------------
__global__ __launch_bounds__(256) void k_pgen(const float* __restrict__ ctxe,
                                              const float* __restrict__ tab,
                                              const int* __restrict__ y,
                                              const float* __restrict__ wc,
                                              const float* __restrict__ wsv,
                                              const float* __restrict__ wy,
                                              const float* __restrict__ pgb,
                                              const float* __restrict__ out,
                                              float* __restrict__ pgen_ws){
  __shared__ float red[4];
  int b = blockIdx.x, tid = threadIdx.x, lane = tid & 63, w = tid >> 6;
  const float* hn = out + (size_t)BB*VSZ + (size_t)b*HIDD;
  const float* emb = tab + (size_t)y[b]*EMBD;
  float acc = 0.f;
  #pragma unroll
  for (int i=0;i<4;i++){
    int d = i*256 + tid;
    acc += ctxe[(size_t)b*HIDD + d]*wc[d] + hn[d]*wsv[d];
  }
  #pragma unroll
  for (int i=0;i<2;i++){
    int d = i*256 + tid;
    acc += emb[d]*wy[d];
  }
  acc = wave_sum(acc);
  if (lane==0) red[w] = acc;
  __syncthreads();
  if (tid==0)
    pgen_ws[b] = sigmoid_f(red[0]+red[1]+red[2]+red[3] + pgb[0]);
}

// ---------------- K9b: per-segment max + sumexp partials (256 blocks) ----------------
__global__ __launch_bounds__(256) void k_vred(const float* __restrict__ out,
                                              float* __restrict__ vm,
                                              float* __restrict__ vs){
  __shared__ float red[8];
  int b = blockIdx.x, seg = blockIdx.y;
  int tid = threadIdx.x, lane = tid & 63, w = tid >> 6;
  const float* row = out + (size_t)b*VSZ;
  int lo = seg*8000, hi = lo + 8000;
  float m = -3.4e38f;
  for (int i=lo+tid; i<hi; i+=256) m = fmaxf(m, row[i]);
  m = wave_max(m);
  if (lane==0) red[w] = m;
  __syncthreads();
  m = fmaxf(fmaxf(red[0],red[1]), fmaxf(red[2],red[3]));
  float s = 0.f;
  for (int i=lo+tid; i<hi; i+=256) s += __expf(row[i]-m);
  s = wave_sum(s);
  if (lane==0) red[4+w] = s;
  __syncthreads();
  if (tid==0){
    vm[b*4+seg] = m;
    vs[b*4+seg] = red[4]+red[5]+red[6]+red[7];
  }
}

// ---------------- K9c: combine partials + scale pass (256 blocks) ----------------
__global__ __launch_bounds__(256) void k_vscale(float* __restrict__ out,
                                                const float* __restrict__ vm,
                                                const float* __restrict__ vs,
                                                const float* __restrict__ pgen_ws){
  int b = blockIdx.x, seg = blockIdx.y;
  int tid = threadIdx.x;
  float m0=vm[b*4+0], m1=vm[b*4+1], m2=vm[b*4+2], m3=vm[b*4+3];
  float M = fmaxf(fmaxf(m0,m1), fmaxf(m2,m3));
  float S = vs[b*4+0]*__expf(m0-M) + vs[b*4+1]*__expf(m1-M)
          + vs[b*4+2]*__expf(m2-M) + vs[b*4+3]*__expf(m3-M);
  float scale = pgen_ws[b] / S;
  float* row = out + (size_t)b*VSZ;
  int lo = seg*8000, hi = lo + 8000;
  for (int i=lo+tid; i<hi; i+=256) row[i] = __expf(row[i]-M)*scale;
}

// ---------------- K10: pointer scatter ----------------
__global__ __launch_bounds__(256) void k_scatter(const int* __restrict__ src_ids,
                                                 const float* __restrict__ att_e,
                                                 const float* __restrict__ pgen_ws,
                                                 float* __restrict__ out){
  int id = blockIdx.x*256 + threadIdx.x;
  int b = id >> 9;
  float pg = pgen_ws[b];
  int sid = src_ids[id];
  float contrib = (1.0f - pg) * att_e[id] * (sid < VSZ ? 1.0f : 0.0f);
  int safe = sid < VSZ-1 ? sid : VSZ-1;
  atomicAdd(&out[(size_t)b*VSZ + safe], contrib);
}

extern "C" void kernel_launch(void* const* d_in, const int* in_sizes, int n_in,
                              void* d_out, int out_size, void* d_ws, size_t ws_size,
                              hipStream_t stream){
  const int*   y     = (const int*)d_in[0];
  const float* h     = (const float*)d_in[1];
  const float* c     = (const float*)d_in[2];
  const float* enc   = (const float*)d_in[3];
  const float* bwd   = (const float*)d_in[4];
  const int*   sids  = (const int*)d_in[5];
  const int*   smask = (const int*)d_in[6];
  const float* tab   = (const float*)d_in[7];
  const float* W_ih  = (const float*)d_in[8];
  const float* W_hh  = (const float*)d_in[9];
  const float* b_ih  = (const float*)d_in[10];
  const float* b_hh  = (const float*)d_in[11];
  const float* Wq_e  = (const float*)d_in[12];
  const float* Wk_e  = (const float*)d_in[13];
  const float* v_e   = (const float*)d_in[14];
  const float* Wq_b  = (const float*)d_in[15];
  const float* Wk_b  = (const float*)d_in[16];
  const float* v_b   = (const float*)d_in[17];
  const float* Wp    = (const float*)d_in[18];
  const float* bp    = (const float*)d_in[19];
  const float* wc    = (const float*)d_in[20];
  const float* wsv   = (const float*)d_in[21];
  const float* wy    = (const float*)d_in[22];
  const float* pgb   = (const float*)d_in[23];
  float* out = (float*)d_out;

  float* W = (float*)d_ws;
  float* ws_qpe  = W; W += 2*BB*HIDD;        // qproj partials (2 K-split slots)
  float* ws_qpb  = W; W += 2*BB*HIDD;
  float* ws_ep   = W; W += 2*8*BB*TSEQ;      // energy partials [att][8][b][t]
  float* ws_atte = W; W += BB*TSEQ;
  float* ws_attb = W; W += BB*TSEQ;
  float* ws_ctxe = W; W += BB*HIDD;
  float* ws_ctxb = W; W += BB*HIDD;
  float* ws_ctxp = W; W += 2*BB*16*1024;     // 2097152 (16 slots)
  float* ws_pgen = W; W += 64;
  float* ws_vm   = W; W += 256;
  float* ws_vs   = W; W += 256;
  float* ws_gp   = W; W += 8*BB*G4;          // 2097152 (8 K-split slots)
  short* xb      = (short*)W; W += (BB*3584)/2;
  short* hb      = (short*)W; W += (BB*HIDD)/2;
  short* pk_e    = (short*)W; W += (HIDD*HIDD)/2;   // packed+swizzled Wk_e bf16
  short* pk_b    = (short*)W; W += (HIDD*HIDD)/2;
  short* pkeys   = (short*)W; W += (2*BB*TSEQ*HIDD)/2;  // 128 MB packed bf16 keys

  k_prep_all<<<33824, 256, 0, stream>>>(Wk_e, Wk_b, enc, bwd, h,
      pk_e, pk_b, pkeys, xb);
  k_mm64<<<dim3(4,2,2), 256, 0, stream>>>(
      xb+2560, 3584, Wq_e, 1024, 1024, ws_qpe, 1024,
      xb+2560, 3584, Wq_b, 1024, 1024, ws_qpb, 1024);
  k_energy<<<4096, 256, 0, stream>>>(pkeys, pk_e, pk_b,
      ws_qpe, ws_qpb, v_e, v_b, ws_ep);
  k_softmax_t<<<dim3(BB,2), 256, 0, stream>>>(ws_ep, smask, ws_atte, ws_attb);
  k_ctx<<<dim3(BB,2,8), 256, 0, stream>>>(pkeys, ws_atte, ws_attb, ws_ctxp);
  k_ctxred<<<512, 256, 0, stream>>>(ws_ctxp, ws_ctxe, ws_ctxb);
  k_prep_x2<<<80, 256, 0, stream>>>(tab, y, ws_ctxe, ws_ctxb, xb);
  k_mm64<<<dim3(16,4,2), 256, 0, stream>>>(
      xb,      3584, W_ih, 2560, 2560, ws_gp,             G4,
      xb+2560, 3584, W_hh, 1024, 1024, ws_gp + 4*BB*G4,   G4);
  k_lstm<<<256, 256, 0, stream>>>(ws_gp, b_ih, b_hh, c, out, hb);
  k_vocab2<<<250, 256, 0, stream>>>(hb, Wp, bp, out);
  k_pgen<<<BB, 256, 0, stream>>>(ws_ctxe, tab, y, wc, wsv, wy, pgb, out, ws_pgen);
  k_vred<<<dim3(BB,4), 256, 0, stream>>>(out, ws_vm, ws_vs);
  k_vscale<<<dim3(BB,4), 256, 0, stream>>>(out, ws_vm, ws_vs, ws_pgen);
  k_scatter<<<128, 256, 0, stream>>>(sids, ws_atte, ws_pgen, out);
}